// Round 6
// baseline (914.690 us; speedup 1.0000x reference)
//
#include <hip/hip_runtime.h>
#include <math.h>

#define BATCH 8
#define C 64
#define NH 8
#define HD 8
#define LTXT 77
#define H0 64
#define W0 64
#define HW0 (H0*W0)

typedef __attribute__((ext_vector_type(8))) short bfrag;    // 8 bf16 (4 VGPR)
typedef __attribute__((ext_vector_type(4))) float ffrag;    // 4 fp32 acc
typedef __attribute__((ext_vector_type(8))) unsigned short us8;
typedef __attribute__((ext_vector_type(4))) unsigned short us4;
typedef __attribute__((ext_vector_type(2))) float f2;

#if defined(__has_builtin)
#if __has_builtin(__builtin_amdgcn_exp2f)
#define EXP2(x) __builtin_amdgcn_exp2f(x)
#else
#define EXP2(x) exp2f(x)
#endif
#else
#define EXP2(x) exp2f(x)
#endif

__device__ __forceinline__ unsigned short f2bf(float f) {
    unsigned u = __builtin_bit_cast(unsigned, f);
    u += 0x7fff + ((u >> 16) & 1);   // RNE
    return (unsigned short)(u >> 16);
}

// ---------------- text projection: tf[b,l,c] = th[b,l,:] . proj_w[c,:] + proj_b[c]
__global__ void text_proj_kernel(const float* __restrict__ th, const float* __restrict__ pw,
                                 const float* __restrict__ pb, float* __restrict__ tf) {
    __shared__ float sh[512];
    int bl = blockIdx.x;
    int c = threadIdx.x;
    const float* row = th + (size_t)bl * 512;
    for (int i = c; i < 512; i += 64) sh[i] = row[i];
    __syncthreads();
    const float* wrow = pw + c * 512;
    float acc = pb[c];
    for (int i = 0; i < 512; i += 4) {
        acc += sh[i] * wrow[i] + sh[i+1] * wrow[i+1] + sh[i+2] * wrow[i+2] + sh[i+3] * wrow[i+3];
    }
    tf[bl * 64 + c] = acc;
}

// ---------------- merged prep: conv_in (blocks 0..8191) + pack_up (8192..9343)
// + pack_final (9344..9379) + pack_proj (9380..9635)
__global__ void __launch_bounds__(256)
prep_kernel(const float* __restrict__ x, const float* __restrict__ cf_w,
            const float* __restrict__ cf_b, float* __restrict__ feat,
            const float* __restrict__ up_w,
            unsigned short* __restrict__ PW1, unsigned short* __restrict__ PW2,
            const float* __restrict__ cl_w, unsigned short* __restrict__ PWF,
            const float* __restrict__ qw, const float* __restrict__ ow,
            unsigned short* __restrict__ PQ, unsigned short* __restrict__ PO) {
    int blk = blockIdx.x;
    if (blk < 8192) {
        // conv_in: x[8,3,64,64] -> feat[8,64,64,64] fp32 NCHW
        int idx = blk * 256 + threadIdx.x;
        int wx = idx & 63;
        int h = (idx >> 6) & 63;
        int o = (idx >> 12) & 63;
        int b = idx >> 18;
        const float* wr = cf_w + o * 27;
        float acc = cf_b[o];
        for (int ci = 0; ci < 3; ci++) {
            for (int ky = 0; ky < 3; ky++) {
                int y = h + ky - 1;
                if ((unsigned)y >= 64u) continue;
                const float* xr = x + (((size_t)b * 3 + ci) * 64 + y) * 64;
                const float* wk = wr + ci * 9 + ky * 3;
                if (wx > 0) acc += xr[wx - 1] * wk[0];
                acc += xr[wx] * wk[1];
                if (wx < 63) acc += xr[wx + 1] * wk[2];
            }
        }
        feat[idx] = acc;
    } else if (blk < 8192 + 1152) {
        int e0 = blk - 8192;
        int st = e0 / 576;
        int e = (e0 % 576) * 256 + threadIdx.x;   // < 147456
        const float* w = up_w + (size_t)st * 147456;
        unsigned short* d = st ? PW2 : PW1;
        int j = e & 7, n = (e >> 3) & 255, q = (e >> 11) & 3, s = (e >> 13) & 1, t = e >> 14;
        int c = n & 63, g = n >> 6;
        int co = 4 * c + g, ci = 32 * s + 8 * q + j;
        d[e] = f2bf(w[co * 576 + ci * 9 + t]);
    } else if (blk < 8192 + 1152 + 36) {
        int e = (blk - 8192 - 1152) * 256 + threadIdx.x;   // < 9216
        int j = e & 7, n = (e >> 3) & 15, q = (e >> 7) & 3, s = (e >> 9) & 1, t = e >> 10;
        int ci = 32 * s + 8 * q + j;
        float v = (n < 3) ? cl_w[n * 576 + ci * 9 + t] : 0.f;
        PWF[e] = f2bf(v);
    } else {
        int e = (blk - 8192 - 1152 - 36) * 256 + threadIdx.x;   // < 65536
        int j = e & 7, n = (e >> 3) & 63, quad = (e >> 9) & 3, kt = (e >> 11) & 1, layer = e >> 12;
        int c = kt * 32 + quad * 8 + j;
        PQ[e] = f2bf(qw[layer * 4096 + n * 64 + c]);
        PO[e] = f2bf(ow[layer * 4096 + n * 64 + c]);
    }
}

// ---------------- K/V for ALL 16 blocks upfront; K pre-scaled by scale*log2(e).
// Interleaved kv[layer][b][tok][head][16] = {k0..k7, v0..v7}: one aligned 64B
// chunk per (token, head).
__global__ void kv_all_kernel(const float* __restrict__ tf,
                              const float* __restrict__ kw, const float* __restrict__ kb,
                              const float* __restrict__ vw, const float* __restrict__ vb,
                              const float* __restrict__ l2w, const float* __restrict__ l2b,
                              float* __restrict__ kvbuf) {
    __shared__ float sh[64];
    int g = blockIdx.x;
    int bl = g % (BATCH * LTXT);
    int blk = g / (BATCH * LTXT);
    int o = threadIdx.x;
    sh[o] = tf[bl * 64 + o];
    __syncthreads();
    const float* kr = kw + blk * 4096 + o * 64;
    const float* vr = vw + blk * 4096 + o * 64;
    float ka = kb[blk * 64 + o], va = vb[blk * 64 + o];
    for (int c2 = 0; c2 < 64; c2++) {
        float t = sh[c2];
        ka += t * kr[c2];
        va += t * vr[c2];
    }
    float s = ka;
    for (int off = 32; off; off >>= 1) s += __shfl_xor(s, off, 64);
    float mean = s * (1.0f / 64.0f);
    float d = ka - mean;
    float s2 = d * d;
    for (int off = 32; off; off >>= 1) s2 += __shfl_xor(s2, off, 64);
    float rstd = rsqrtf(s2 * (1.0f / 64.0f) + 1e-5f);
    float kn = (d * rstd * l2w[blk * 64 + o] + l2b[blk * 64 + o]) * 0.51006973f;
    // interleaved write: token row = 128 floats = 8 heads x {8 k, 8 v}
    size_t base = ((size_t)blk * (BATCH * LTXT) + bl) * 128;
    int hd = o >> 3, ch = o & 7;
    kvbuf[base + hd * 16 + ch]     = kn;
    kvbuf[base + hd * 16 + 8 + ch] = va;
}

// ---------------- ALL 16 attention blocks fused. RESTRUCTURED: 32-px tiles,
// 512 threads = 8 waves, 1024 blocks (4/CU). Wave = one head; 64 lanes =
// 32 px x 2 token-halves (lane>=32 -> tokens 39..76). KV addresses are now
// per-lane -> VMEM global_load path (VGPR-budgeted, vmcnt-pipelined) instead
// of the SGPR-capped s_load chain that plateaued R4/R5. Softmax halves combine
// in-register via shfl_xor(32) -> no so/ss1 LDS exchange, 4 barriers/layer,
// perfectly balanced waves. Summation grouping preserved -> bit-identical.
__global__ void __launch_bounds__(512, 8)
attn_all_kernel(const float* __restrict__ feat,
                const float* __restrict__ kvbuf,
                const unsigned short* __restrict__ PQ, const unsigned short* __restrict__ PO,
                const float* __restrict__ qb_a, const float* __restrict__ ob_a,
                const float* __restrict__ l1w_a, const float* __restrict__ l1b_a,
                unsigned short* __restrict__ X1) {
    __shared__ __attribute__((aligned(16))) unsigned short sfb[32][72]; // residual bf16 [p][c]
    __shared__ __attribute__((aligned(16))) unsigned short sob[32][72]; // attn-out bf16 [p][c]
    __shared__ __attribute__((aligned(16))) float qf[64][36];           // raw q / out-proj [c][p]
    __shared__ __attribute__((aligned(16))) float red[2][4][32];        // LN partials [s][nt][p]

    int b = blockIdx.x >> 7;            // 128 tiles per batch
    int tile = blockIdx.x & 127;
    int n0 = tile << 5;                 // 32 px per tile
    int wv = __builtin_amdgcn_readfirstlane(threadIdx.x >> 6);  // wave 0..7
    int lane = threadIdx.x & 63;
    int px = lane & 31;                 // pixel within tile
    int th = lane >> 5;                 // token half (0: 0..38, 1: 39..76)
    int quad = lane >> 4, n16 = lane & 15;
    int mt = wv >> 2, nt = wv & 3;      // GEMM C-tile role (M=32: mt 0..1; N=64: nt 0..3)
    int cch = nt * 16 + n16;            // GEMM output channel
    int p0 = mt * 16 + quad * 4;        // GEMM output pixel base (0..28)
    int h = wv;                         // head
    int a0 = h * 8;
    int co = wv * 8 + th * 4;           // residual-ownership channels co..co+3
    const float* fbase = feat + ((size_t)b << 18) + n0;

    // stage: residual regs + bf16 mirror
    float rres[4];
#pragma unroll
    for (int j = 0; j < 4; j++) rres[j] = fbase[(co + j) * HW0 + px];
    {
        us4 v;
#pragma unroll
        for (int j = 0; j < 4; j++) v[j] = f2bf(rres[j]);
        *(us4*)&sfb[px][co] = v;
    }

    const float pxk = 0.05f / 63.0f;
    float pex_base = (float)((tile & 1) * 32) * pxk;   // x-offset of this tile
    float pey = (float)(tile >> 1) * pxk;              // y position
    __syncthreads();

#pragma unroll 1
    for (int layer = 0; layer < 16; layer++) {
        const float* qb = qb_a + layer * 64;
        const float* ob = ob_a + layer * 64;
        const float* l1w = l1w_a + layer * 64;
        const float* l1b = l1b_a + layer * 64;

        // ---- A: q-proj GEMM + in-wave LN partial reduction in epilogue
        {
            bfrag af0 = *(const bfrag*)&sfb[mt * 16 + n16][quad * 8];
            bfrag af1 = *(const bfrag*)&sfb[mt * 16 + n16][32 + quad * 8];
            const unsigned short* bq = PQ + layer * 4096 + (size_t)((quad * 64) + cch) * 8;
            bfrag bf0 = *(const bfrag*)bq;
            bfrag bf1 = *(const bfrag*)(bq + 2048);   // kt=1 chunk
            ffrag cc = (ffrag)0.f;
            cc = __builtin_amdgcn_mfma_f32_16x16x32_bf16(af0, bf0, cc, 0, 0, 0);
            cc = __builtin_amdgcn_mfma_f32_16x16x32_bf16(af1, bf1, cc, 0, 0, 0);
            float qbv = qb[cch];
            float pe0 = (nt < 2) ? pex_base + (float)p0 * pxk : pey;
            float ped = (nt < 2) ? pxk : 0.f;
            float ov[4];
            ov[0] = cc[0] + qbv + pe0;
            ov[1] = cc[1] + qbv + pe0 + ped;
            ov[2] = cc[2] + qbv + pe0 + 2.f * ped;
            ov[3] = cc[3] + qbv + pe0 + 3.f * ped;
            float4 o4 = {ov[0], ov[1], ov[2], ov[3]};
            *(float4*)&qf[cch][p0] = o4;

            // channel-sum over the 16 n16 lanes (same quad), per pixel r
            float sv[4], sq[4];
#pragma unroll
            for (int r = 0; r < 4; r++) {
                float s = ov[r], s2v = ov[r] * ov[r];
                s += __shfl_xor(s, 1);  s2v += __shfl_xor(s2v, 1);
                s += __shfl_xor(s, 2);  s2v += __shfl_xor(s2v, 2);
                s += __shfl_xor(s, 4);  s2v += __shfl_xor(s2v, 4);
                s += __shfl_xor(s, 8);  s2v += __shfl_xor(s2v, 8);
                sv[r] = s; sq[r] = s2v;
            }
            if (n16 == 0) {
                *(float4*)&red[0][nt][p0] = (float4){sv[0], sv[1], sv[2], sv[3]};
                *(float4*)&red[1][nt][p0] = (float4){sq[0], sq[1], sq[2], sq[3]};
            }
        }
        __syncthreads();   // B1: qf + red ready

        // ---- C: attention; lane = (px, token-half); combine halves via shfl
        {
            float ts = red[0][0][px] + red[0][1][px] + red[0][2][px] + red[0][3][px];
            float ts2 = red[1][0][px] + red[1][1][px] + red[1][2][px] + red[1][3][px];
            float mean = ts * (1.0f / 64.0f);
            float var = ts2 * (1.0f / 64.0f) - mean * mean;
            float rstd = rsqrtf(var + 1e-5f);

            f2 qv[4];
#pragma unroll
            for (int j = 0; j < 4; j++) {
                float qa  = (qf[a0 + 2 * j][px]     - mean) * rstd * l1w[a0 + 2 * j]     + l1b[a0 + 2 * j];
                float qbv = (qf[a0 + 2 * j + 1][px] - mean) * rstd * l1w[a0 + 2 * j + 1] + l1b[a0 + 2 * j + 1];
                qv[j][0] = qa;
                qv[j][1] = qbv;
            }
            // per-lane token base: th0 -> 0.., th1 -> 39..  (VMEM path)
            const float* kvb = kvbuf + ((size_t)layer * BATCH * LTXT + (size_t)b * LTXT) * 128 + h * 16
                             + (size_t)(th * 39) * 128;
            float ssum = 0.f;
            f2 acc2[4] = {(f2)0.f, (f2)0.f, (f2)0.f, (f2)0.f};
            for (int i = 0; i < 38; i++) {
                const float4* r = (const float4*)(kvb + (size_t)i * 128);
                float4 k0 = r[0], k1 = r[1], v0 = r[2], v1 = r[3];
                f2 d2 = qv[0] * (f2){k0.x, k0.y};
                d2 += qv[1] * (f2){k0.z, k0.w};
                d2 += qv[2] * (f2){k1.x, k1.y};
                d2 += qv[3] * (f2){k1.z, k1.w};
                float e = EXP2(d2[0] + d2[1]);
                ssum += e;
                f2 e2 = {e, e};
                acc2[0] += e2 * (f2){v0.x, v0.y};
                acc2[1] += e2 * (f2){v0.z, v0.w};
                acc2[2] += e2 * (f2){v1.x, v1.y};
                acc2[3] += e2 * (f2){v1.z, v1.w};
            }
            {   // extra token: th0 -> token 38 (valid); th1 -> masked (clamped load)
                size_t ioff = (size_t)(th ? 37 : 38) * 128;   // th1 re-reads token 76 (finite)
                const float4* r = (const float4*)(kvb + ioff);
                float4 k0 = r[0], k1 = r[1], v0 = r[2], v1 = r[3];
                f2 d2 = qv[0] * (f2){k0.x, k0.y};
                d2 += qv[1] * (f2){k0.z, k0.w};
                d2 += qv[2] * (f2){k1.x, k1.y};
                d2 += qv[3] * (f2){k1.z, k1.w};
                float e = EXP2(d2[0] + d2[1]);
                if (th) e = 0.f;
                ssum += e;
                f2 e2 = {e, e};
                acc2[0] += e2 * (f2){v0.x, v0.y};
                acc2[1] += e2 * (f2){v0.z, v0.w};
                acc2[2] += e2 * (f2){v1.x, v1.y};
                acc2[3] += e2 * (f2){v1.z, v1.w};
            }
            // combine halves in-register: lane p <-> lane p+32
            float stot = ssum + __shfl_xor(ssum, 32, 64);
            f2 atot[4];
#pragma unroll
            for (int j = 0; j < 4; j++) {
                atot[j][0] = acc2[j][0] + __shfl_xor(acc2[j][0], 32, 64);
                atot[j][1] = acc2[j][1] + __shfl_xor(acc2[j][1], 32, 64);
            }
            if (!th) {
                float inv = 1.0f / stot;
                us8 v;
#pragma unroll
                for (int j = 0; j < 4; j++) {
                    v[2*j]   = f2bf(atot[j][0] * inv);
                    v[2*j+1] = f2bf(atot[j][1] * inv);
                }
                *(us8*)&sob[px][a0] = v;
            }
        }
        __syncthreads();   // B5: sob ready

        // ---- D: out-proj GEMM (A from sob), result -> qf (reused as scratch)
        {
            bfrag af0 = *(const bfrag*)&sob[mt * 16 + n16][quad * 8];
            bfrag af1 = *(const bfrag*)&sob[mt * 16 + n16][32 + quad * 8];
            const unsigned short* bo = PO + layer * 4096 + (size_t)((quad * 64) + cch) * 8;
            bfrag bf0 = *(const bfrag*)bo;
            bfrag bf1 = *(const bfrag*)(bo + 2048);
            ffrag cc = (ffrag)0.f;
            cc = __builtin_amdgcn_mfma_f32_16x16x32_bf16(af0, bf0, cc, 0, 0, 0);
            cc = __builtin_amdgcn_mfma_f32_16x16x32_bf16(af1, bf1, cc, 0, 0, 0);
            float obv = ob[cch];
            float4 o4;
            o4.x = cc[0] + obv; o4.y = cc[1] + obv; o4.z = cc[2] + obv; o4.w = cc[3] + obv;
            *(float4*)&qf[cch][p0] = o4;
        }
        __syncthreads();   // B6: qf ready

        // ---- E: residual update in regs + refresh bf16 mirror
        {
            us4 v;
#pragma unroll
            for (int j = 0; j < 4; j++) {
                rres[j] += qf[co + j][px];
                v[j] = f2bf(rres[j]);
            }
            *(us4*)&sfb[px][co] = v;
        }
        __syncthreads();   // B7: sfb ready for next layer
    }

    // final write: NHWC bf16
    us4 v;
#pragma unroll
    for (int j = 0; j < 4; j++) v[j] = f2bf(rres[j]);
    *(us4*)(X1 + ((size_t)(b * 4096 + n0 + px)) * 64 + co) = v;
}

// ---------------- upsample conv as 9-tap implicit GEMM, MFMA 16x16x32 bf16.
// MERGED: one 512-thread block covers all 256 n' -> input staged once.
__global__ void __launch_bounds__(512)
upconv_mfma_kernel(const unsigned short* __restrict__ X, const unsigned short* __restrict__ Bp,
                   const float* __restrict__ bias, unsigned short* __restrict__ Y,
                   int Hin, int Win) {
    __shared__ __attribute__((aligned(16))) unsigned short sx[3 * 66 * 72];  // 28.5 KB

    int wv = threadIdx.x >> 6;          // wave 0..7
    int lane = threadIdx.x & 63;
    int q = lane >> 4, n16 = lane & 15;
    int m0 = blockIdx.x * 64;
    int hw = Hin * Win;
    int b = m0 / hw, rem = m0 % hw;
    int h = rem / Win, w0 = rem % Win;
    const unsigned short* Xb = X + (size_t)b * hw * 64;

    // stage 3 rows x 66 px x 64 ch (zero halo), ch-padded to 72
    const us8 z8 = (us8)(unsigned short)0;
    for (int e = threadIdx.x; e < 1584; e += 512) {
        int ch8 = e & 7;
        int pxi = (e >> 3) % 66;
        int row = e / 528;
        int hh = h + row - 1, wp = w0 + pxi - 1;
        us8 v = z8;
        if ((unsigned)hh < (unsigned)Hin && (unsigned)wp < (unsigned)Win)
            v = *(const us8*)(Xb + ((size_t)hh * Win + wp) * 64 + ch8 * 8);
        *(us8*)&sx[row * 4752 + pxi * 72 + ch8 * 8] = v;
    }
    __syncthreads();

    ffrag acc[4][2];
#pragma unroll
    for (int i = 0; i < 4; i++)
#pragma unroll
        for (int j2 = 0; j2 < 2; j2++) acc[i][j2] = (ffrag)0.f;

    int npb = wv * 32;   // n' base for this wave (covers all 256 across 8 waves)

    for (int t = 0; t < 9; t++) {
        int dy = t / 3, dx = t % 3;
        bfrag af[4][2];
#pragma unroll
        for (int mt = 0; mt < 4; mt++) {
            const unsigned short* sp = &sx[dy * 4752 + (mt * 16 + n16 + dx) * 72 + q * 8];
            af[mt][0] = *(const bfrag*)sp;
            af[mt][1] = *(const bfrag*)(sp + 32);
        }
#pragma unroll
        for (int s = 0; s < 2; s++) {
#pragma unroll
            for (int nt = 0; nt < 2; nt++) {
                bfrag bf = *(const bfrag*)(Bp + (size_t)((((t * 2 + s) * 4 + q) * 256) + npb + nt * 16 + n16) * 8);
#pragma unroll
                for (int mt = 0; mt < 4; mt++)
                    acc[mt][nt] = __builtin_amdgcn_mfma_f32_16x16x32_bf16(af[mt][s], bf, acc[mt][nt], 0, 0, 0);
            }
        }
    }

    int g = wv >> 1;                   // g' = 2*r1 + r2
    int r1 = wv >> 2, r2 = (wv >> 1) & 1;
    int cbase = (wv & 1) * 32;
    float bv[2];
#pragma unroll
    for (int nt = 0; nt < 2; nt++) bv[nt] = bias[4 * (cbase + nt * 16 + n16) + g];
    int Wo = Win * 2;
    unsigned short* Yb = Y + ((size_t)b * Hin * 2 * Wo + (size_t)(2 * h + r1) * Wo + r2) * 64;
#pragma unroll
    for (int mt = 0; mt < 4; mt++) {
#pragma unroll
        for (int r = 0; r < 4; r++) {
            int m = mt * 16 + q * 4 + r;   // C/D: row = quad*4 + reg
            unsigned short* dst = Yb + (size_t)(2 * (w0 + m)) * 64;
#pragma unroll
            for (int nt = 0; nt < 2; nt++) {
                float v = acc[mt][nt][r] + bv[nt];
                v = fmaxf(v, 0.f);
                dst[cbase + nt * 16 + n16] = f2bf(v);
            }
        }
    }
}

// ---------------- final conv as 9-tap implicit GEMM, N=16 (3 real), fp32 NCHW out
// 2D tile: 64 px x 4 rows per block; 6 rows x 66 px staged in LDS (57 KB).
__global__ void __launch_bounds__(256)
final_mfma_kernel(const unsigned short* __restrict__ X, const unsigned short* __restrict__ Bp,
                  const float* __restrict__ bias, float* __restrict__ out) {
    __shared__ __attribute__((aligned(16))) unsigned short sx[6 * 66 * 72];  // 57 KB

    int t0 = blockIdx.x;
    int wseg = t0 & 3;
    int rg = (t0 >> 2) & 63;
    int b = t0 >> 8;
    int y0 = rg * 4, w0 = wseg * 64;
    int wv = threadIdx.x >> 6, lane = threadIdx.x & 63;
    int q = lane >> 4, n16 = lane & 15;
    const unsigned short* Xb = X + (size_t)b * 65536 * 64;

    // stage 6 rows x 66 px x 64 ch (zero halo), ch pitch 72
    const us8 z8 = (us8)(unsigned short)0;
    for (int e = threadIdx.x; e < 3168; e += 256) {
        int ch8 = e & 7;
        int pxi = (e >> 3) % 66;
        int row = e / 528;
        int hh = y0 - 1 + row, wp = w0 - 1 + pxi;
        us8 v = z8;
        if ((unsigned)hh < 256u && (unsigned)wp < 256u)
            v = *(const us8*)(Xb + ((size_t)hh * 256 + wp) * 64 + ch8 * 8);
        *(us8*)&sx[row * 4752 + pxi * 72 + ch8 * 8] = v;
    }
    __syncthreads();

    // wave wv handles row y0+wv, 64 px
    ffrag acc[4];
#pragma unroll
    for (int i = 0; i < 4; i++) acc[i] = (ffrag)0.f;

    for (int t = 0; t < 9; t++) {
        int dy = t / 3, dx = t % 3;
        bfrag af[4][2];
#pragma unroll
        for (int mt = 0; mt < 4; mt++) {
            const unsigned short* sp = &sx[(wv + dy) * 4752 + (mt * 16 + n16 + dx) * 72 + q * 8];
            af[mt][0] = *(const bfrag*)sp;
            af[mt][1] = *(const bfrag*)(sp + 32);
        }
#pragma unroll
        for (int s = 0; s < 2; s++) {
            bfrag bf = *(const bfrag*)(Bp + (size_t)((((t * 2 + s) * 4 + q) * 16) + n16) * 8);
#pragma unroll
            for (int mt = 0; mt < 4; mt++)
                acc[mt] = __builtin_amdgcn_mfma_f32_16x16x32_bf16(af[mt][s], bf, acc[mt], 0, 0, 0);
        }
    }

    if (n16 < 3) {
        float bj = bias[n16];
        float* ob = out + (((size_t)b * 3 + n16) * 256 + (y0 + wv)) * 256;
#pragma unroll
        for (int mt = 0; mt < 4; mt++)
#pragma unroll
            for (int r = 0; r < 4; r++)
                ob[w0 + mt * 16 + q * 4 + r] = acc[mt][r] + bj;
    }
}

extern "C" void kernel_launch(void* const* d_in, const int* in_sizes, int n_in,
                              void* d_out, int out_size, void* d_ws, size_t ws_size,
                              hipStream_t stream) {
    const float* x      = (const float*)d_in[0];
    const float* th     = (const float*)d_in[1];
    const float* proj_w = (const float*)d_in[2];
    const float* proj_b = (const float*)d_in[3];
    const float* cf_w   = (const float*)d_in[4];
    const float* cf_b   = (const float*)d_in[5];
    const float* qw     = (const float*)d_in[6];
    const float* qb     = (const float*)d_in[7];
    const float* kw     = (const float*)d_in[8];
    const float* kb     = (const float*)d_in[9];
    const float* vw     = (const float*)d_in[10];
    const float* vb     = (const float*)d_in[11];
    const float* ow     = (const float*)d_in[12];
    const float* ob     = (const float*)d_in[13];
    const float* l1w    = (const float*)d_in[14];
    const float* l1b    = (const float*)d_in[15];
    const float* l2w    = (const float*)d_in[16];
    const float* l2b    = (const float*)d_in[17];
    const float* up_w   = (const float*)d_in[18];
    const float* up_b   = (const float*)d_in[19];
    const float* cl_w   = (const float*)d_in[20];
    const float* cl_b   = (const float*)d_in[21];

    float* ws   = (float*)d_ws;
    float* feat = ws;                         // 2,097,152 f
    float* tf   = feat + 2097152;             // 39,424 f
    float* kvbuf = tf + 39424;                // 1,261,568 f (16*8*77*128)
    unsigned short* X1  = (unsigned short*)(kvbuf + 1261568);  // 2,097,152 us
    unsigned short* X2  = X1 + 2097152;       // 8,388,608 us
    unsigned short* X3  = X2 + 8388608;       // 33,554,432 us
    unsigned short* PW1 = X3 + 33554432;      // 147,456 us
    unsigned short* PW2 = PW1 + 147456;       // 147,456 us
    unsigned short* PWF = PW2 + 147456;       // 9,216 us
    unsigned short* PQ  = PWF + 9216;         // 65,536 us
    unsigned short* PO  = PQ + 65536;         // 65,536 us

    hipLaunchKernelGGL(prep_kernel, dim3(8192 + 1152 + 36 + 256), dim3(256), 0, stream,
                       x, cf_w, cf_b, feat, up_w, PW1, PW2, cl_w, PWF, qw, ow, PQ, PO);
    hipLaunchKernelGGL(text_proj_kernel, dim3(BATCH * LTXT), dim3(64), 0, stream,
                       th, proj_w, proj_b, tf);
    hipLaunchKernelGGL(kv_all_kernel, dim3(16 * BATCH * LTXT), dim3(64), 0, stream,
                       tf, kw, kb, vw, vb, l2w, l2b, kvbuf);

    hipLaunchKernelGGL(attn_all_kernel, dim3(BATCH * (HW0 / 32)), dim3(512), 0, stream,
                       feat, kvbuf, PQ, PO, qb, ob, l1w, l1b, X1);

    hipLaunchKernelGGL(upconv_mfma_kernel, dim3(BATCH * 64 * 64 / 64), dim3(512), 0, stream,
                       X1, PW1, up_b, X2, 64, 64);
    hipLaunchKernelGGL(upconv_mfma_kernel, dim3(BATCH * 128 * 128 / 64), dim3(512), 0, stream,
                       X2, PW2, up_b + 256, X3, 128, 128);
    hipLaunchKernelGGL(final_mfma_kernel, dim3(BATCH * 64 * 4), dim3(256), 0, stream,
                       X3, PWF, cl_b, (float*)d_out);
}

// Round 7
// 542.101 us; speedup vs baseline: 1.6873x; 1.6873x over previous
//
#include <hip/hip_runtime.h>
#include <math.h>

#define BATCH 8
#define C 64
#define NH 8
#define HD 8
#define LTXT 77
#define H0 64
#define W0 64
#define HW0 (H0*W0)

typedef __attribute__((ext_vector_type(8))) short bfrag;    // 8 bf16 (4 VGPR)
typedef __attribute__((ext_vector_type(4))) float ffrag;    // 4 fp32 acc
typedef __attribute__((ext_vector_type(8))) unsigned short us8;
typedef __attribute__((ext_vector_type(4))) unsigned short us4;
typedef __attribute__((ext_vector_type(2))) float f2;

#if defined(__has_builtin)
#if __has_builtin(__builtin_amdgcn_exp2f)
#define EXP2(x) __builtin_amdgcn_exp2f(x)
#else
#define EXP2(x) exp2f(x)
#endif
#if __has_builtin(__builtin_amdgcn_fdot2_f32_bf16)
#define USE_DOT2 1
typedef __bf16 bf2v __attribute__((ext_vector_type(2)));
#endif
#else
#define EXP2(x) exp2f(x)
#endif

__device__ __forceinline__ unsigned short f2bf(float f) {
    unsigned u = __builtin_bit_cast(unsigned, f);
    u += 0x7fff + ((u >> 16) & 1);   // RNE
    return (unsigned short)(u >> 16);
}

// unpack a u32 holding 2 bf16 into f2 {lo, hi}
__device__ __forceinline__ f2 bfp2f2(unsigned w) {
    f2 r;
    r[0] = __builtin_bit_cast(float, w << 16);
    r[1] = __builtin_bit_cast(float, w & 0xffff0000u);
    return r;
}

// ---------------- text projection: tf[b,l,c] = th[b,l,:] . proj_w[c,:] + proj_b[c]
__global__ void text_proj_kernel(const float* __restrict__ th, const float* __restrict__ pw,
                                 const float* __restrict__ pb, float* __restrict__ tf) {
    __shared__ float sh[512];
    int bl = blockIdx.x;
    int c = threadIdx.x;
    const float* row = th + (size_t)bl * 512;
    for (int i = c; i < 512; i += 64) sh[i] = row[i];
    __syncthreads();
    const float* wrow = pw + c * 512;
    float acc = pb[c];
    for (int i = 0; i < 512; i += 4) {
        acc += sh[i] * wrow[i] + sh[i+1] * wrow[i+1] + sh[i+2] * wrow[i+2] + sh[i+3] * wrow[i+3];
    }
    tf[bl * 64 + c] = acc;
}

// ---------------- merged prep: conv_in (blocks 0..8191) + pack_up (8192..9343)
// + pack_final (9344..9379) + pack_proj (9380..9635)
__global__ void __launch_bounds__(256)
prep_kernel(const float* __restrict__ x, const float* __restrict__ cf_w,
            const float* __restrict__ cf_b, float* __restrict__ feat,
            const float* __restrict__ up_w,
            unsigned short* __restrict__ PW1, unsigned short* __restrict__ PW2,
            const float* __restrict__ cl_w, unsigned short* __restrict__ PWF,
            const float* __restrict__ qw, const float* __restrict__ ow,
            unsigned short* __restrict__ PQ, unsigned short* __restrict__ PO) {
    int blk = blockIdx.x;
    if (blk < 8192) {
        // conv_in: x[8,3,64,64] -> feat[8,64,64,64] fp32 NCHW
        int idx = blk * 256 + threadIdx.x;
        int wx = idx & 63;
        int h = (idx >> 6) & 63;
        int o = (idx >> 12) & 63;
        int b = idx >> 18;
        const float* wr = cf_w + o * 27;
        float acc = cf_b[o];
        for (int ci = 0; ci < 3; ci++) {
            for (int ky = 0; ky < 3; ky++) {
                int y = h + ky - 1;
                if ((unsigned)y >= 64u) continue;
                const float* xr = x + (((size_t)b * 3 + ci) * 64 + y) * 64;
                const float* wk = wr + ci * 9 + ky * 3;
                if (wx > 0) acc += xr[wx - 1] * wk[0];
                acc += xr[wx] * wk[1];
                if (wx < 63) acc += xr[wx + 1] * wk[2];
            }
        }
        feat[idx] = acc;
    } else if (blk < 8192 + 1152) {
        int e0 = blk - 8192;
        int st = e0 / 576;
        int e = (e0 % 576) * 256 + threadIdx.x;   // < 147456
        const float* w = up_w + (size_t)st * 147456;
        unsigned short* d = st ? PW2 : PW1;
        int j = e & 7, n = (e >> 3) & 255, q = (e >> 11) & 3, s = (e >> 13) & 1, t = e >> 14;
        int c = n & 63, g = n >> 6;
        int co = 4 * c + g, ci = 32 * s + 8 * q + j;
        d[e] = f2bf(w[co * 576 + ci * 9 + t]);
    } else if (blk < 8192 + 1152 + 36) {
        int e = (blk - 8192 - 1152) * 256 + threadIdx.x;   // < 9216
        int j = e & 7, n = (e >> 3) & 15, q = (e >> 7) & 3, s = (e >> 9) & 1, t = e >> 10;
        int ci = 32 * s + 8 * q + j;
        float v = (n < 3) ? cl_w[n * 576 + ci * 9 + t] : 0.f;
        PWF[e] = f2bf(v);
    } else {
        int e = (blk - 8192 - 1152 - 36) * 256 + threadIdx.x;   // < 65536
        int j = e & 7, n = (e >> 3) & 63, quad = (e >> 9) & 3, kt = (e >> 11) & 1, layer = e >> 12;
        int c = kt * 32 + quad * 8 + j;
        PQ[e] = f2bf(qw[layer * 4096 + n * 64 + c]);
        PO[e] = f2bf(ow[layer * 4096 + n * 64 + c]);
    }
}

// ---------------- K/V for ALL 16 blocks upfront; K pre-scaled by scale*log2(e).
// NEW: bf16 interleaved kvi[layer][b][tok][head][{k0..7,v0..7}] -> 32 B per
// (token, head); token row = 256 B. Feeds per-layer LDS staging in attn.
__global__ void kv_all_kernel(const float* __restrict__ tf,
                              const float* __restrict__ kw, const float* __restrict__ kb,
                              const float* __restrict__ vw, const float* __restrict__ vb,
                              const float* __restrict__ l2w, const float* __restrict__ l2b,
                              unsigned short* __restrict__ kvi) {
    __shared__ float sh[64];
    int g = blockIdx.x;
    int bl = g % (BATCH * LTXT);
    int blk = g / (BATCH * LTXT);
    int o = threadIdx.x;
    sh[o] = tf[bl * 64 + o];
    __syncthreads();
    const float* kr = kw + blk * 4096 + o * 64;
    const float* vr = vw + blk * 4096 + o * 64;
    float ka = kb[blk * 64 + o], va = vb[blk * 64 + o];
    for (int c2 = 0; c2 < 64; c2++) {
        float t = sh[c2];
        ka += t * kr[c2];
        va += t * vr[c2];
    }
    float s = ka;
    for (int off = 32; off; off >>= 1) s += __shfl_xor(s, off, 64);
    float mean = s * (1.0f / 64.0f);
    float d = ka - mean;
    float s2 = d * d;
    for (int off = 32; off; off >>= 1) s2 += __shfl_xor(s2, off, 64);
    float rstd = rsqrtf(s2 * (1.0f / 64.0f) + 1e-5f);
    float kn = (d * rstd * l2w[blk * 64 + o] + l2b[blk * 64 + o]) * 0.51006973f;
    // interleaved bf16 write: token row = 128 us = 8 heads x {8 k, 8 v}
    size_t base = ((size_t)blk * (BATCH * LTXT) + bl) * 128;
    int hd = o >> 3, ch = o & 7;
    kvi[base + hd * 16 + ch]     = f2bf(kn);
    kvi[base + hd * 16 + 8 + ch] = f2bf(va);
}

// ---------------- ALL 16 attention blocks fused, 1024 threads = 16 waves.
// R5 structure, but KV comes from a per-layer LDS stage (19.7 KB bf16):
// wave-uniform ds_read_b128 broadcasts replace the SGPR-capped s_load chain
// (R5's plateau) without R6's per-lane VMEM disaster. Staging loads issue
// before phase A and hide under the q-proj MFMA; B1 syncs. 2-token body.
// K dot via fdot2 bf16 (fallback: unpack); V unpacked to f32 (R1-proven).
__global__ void __launch_bounds__(1024, 8)
attn_all_kernel(const float* __restrict__ feat,
                const unsigned short* __restrict__ kvi,
                const unsigned short* __restrict__ PQ, const unsigned short* __restrict__ PO,
                const float* __restrict__ qb_a, const float* __restrict__ ob_a,
                const float* __restrict__ l1w_a, const float* __restrict__ l1b_a,
                unsigned short* __restrict__ X1) {
    __shared__ __attribute__((aligned(16))) unsigned short sfb[64][72]; // residual bf16 [p][c]
    __shared__ __attribute__((aligned(16))) unsigned short sob[64][72]; // attn-out bf16 [p][c]
    __shared__ __attribute__((aligned(16))) float qf[64][68];           // raw q / out-proj [c][p]
    __shared__ float so[64][64];        // half-1 raw acc exchange [c][p]
    __shared__ __attribute__((aligned(16))) float red[2][4][64];        // LN partials [s][nt][p]
    __shared__ float ss1[8][64];        // half-1 softmax denominators
    __shared__ __attribute__((aligned(16))) unsigned short skv[LTXT * 128]; // 19.7 KB KV stage

    int b = blockIdx.x >> 6;
    int tile = blockIdx.x & 63;
    int n0 = tile << 6;
    int wv = __builtin_amdgcn_readfirstlane(threadIdx.x >> 6);  // wave 0..15
    int lane = threadIdx.x & 63;
    int p = lane;
    int quad = lane >> 4, n16 = lane & 15;
    int mt = wv >> 2, nt = wv & 3;      // GEMM C-tile role
    int o0 = wv * 4;                    // ownership role: channels o0..o0+3, pixel p
    int h = wv >> 1, half = wv & 1;     // attention role
    int a0 = h * 8;
    const float* fbase = feat + ((size_t)b << 18) + n0;

    // stage: residual regs + bf16 mirror
    float rres[4];
#pragma unroll
    for (int j = 0; j < 4; j++) rres[j] = fbase[(o0 + j) * HW0 + p];
    {
        us4 v;
#pragma unroll
        for (int j = 0; j < 4; j++) v[j] = f2bf(rres[j]);
        *(us4*)&sfb[p][o0] = v;
    }

    const float pxk = 0.05f / 63.0f;
    float py005 = (float)tile * pxk;
    __syncthreads();

#pragma unroll 1
    for (int layer = 0; layer < 16; layer++) {
        const float* qb = qb_a + layer * 64;
        const float* ob = ob_a + layer * 64;
        const float* l1w = l1w_a + layer * 64;
        const float* l1b = l1b_a + layer * 64;

        // ---- KV stage: 1232 x 16B chunks, issued before phase A (hides under MFMA)
        {
            const us8* gk = (const us8*)(kvi + (((size_t)layer * BATCH + b) * LTXT) * 128);
            us8* sk = (us8*)skv;
            int e = threadIdx.x;
            us8 c0 = gk[e];
            us8 c1 = (e + 1024 < 1232) ? gk[e + 1024] : c0;
            sk[e] = c0;
            if (e + 1024 < 1232) sk[e + 1024] = c1;
        }

        // ---- A: q-proj GEMM + in-wave LN partial reduction in epilogue
        {
            bfrag af0 = *(const bfrag*)&sfb[mt * 16 + n16][quad * 8];
            bfrag af1 = *(const bfrag*)&sfb[mt * 16 + n16][32 + quad * 8];
            const unsigned short* bq = PQ + layer * 4096 + (size_t)((quad * 64) + nt * 16 + n16) * 8;
            bfrag bf0 = *(const bfrag*)bq;
            bfrag bf1 = *(const bfrag*)(bq + 2048);   // kt=1 chunk
            ffrag cc = (ffrag)0.f;
            cc = __builtin_amdgcn_mfma_f32_16x16x32_bf16(af0, bf0, cc, 0, 0, 0);
            cc = __builtin_amdgcn_mfma_f32_16x16x32_bf16(af1, bf1, cc, 0, 0, 0);
            int cch = nt * 16 + n16;
            float qbv = qb[cch];
            int p0 = mt * 16 + quad * 4;
            float pe0 = (nt < 2) ? (float)p0 * pxk : py005;
            float ped = (nt < 2) ? pxk : 0.f;
            float ov[4];
            ov[0] = cc[0] + qbv + pe0;
            ov[1] = cc[1] + qbv + pe0 + ped;
            ov[2] = cc[2] + qbv + pe0 + 2.f * ped;
            ov[3] = cc[3] + qbv + pe0 + 3.f * ped;
            float4 o4 = {ov[0], ov[1], ov[2], ov[3]};
            *(float4*)&qf[cch][p0] = o4;

            // channel-sum over the 16 n16 lanes (same quad), per pixel r
            float sv[4], sq[4];
#pragma unroll
            for (int r = 0; r < 4; r++) {
                float s = ov[r], s2v = ov[r] * ov[r];
                s += __shfl_xor(s, 1);  s2v += __shfl_xor(s2v, 1);
                s += __shfl_xor(s, 2);  s2v += __shfl_xor(s2v, 2);
                s += __shfl_xor(s, 4);  s2v += __shfl_xor(s2v, 4);
                s += __shfl_xor(s, 8);  s2v += __shfl_xor(s2v, 8);
                sv[r] = s; sq[r] = s2v;
            }
            if (n16 == 0) {
                *(float4*)&red[0][nt][p0] = (float4){sv[0], sv[1], sv[2], sv[3]};
                *(float4*)&red[1][nt][p0] = (float4){sq[0], sq[1], sq[2], sq[3]};
            }
        }
        __syncthreads();   // B1: qf + red + skv ready

        // ---- C: attention, wave = (head, token-half); stats + normalize inline
        {
            float ts = red[0][0][p] + red[0][1][p] + red[0][2][p] + red[0][3][p];
            float ts2 = red[1][0][p] + red[1][1][p] + red[1][2][p] + red[1][3][p];
            float mean = ts * (1.0f / 64.0f);
            float var = ts2 * (1.0f / 64.0f) - mean * mean;
            float rstd = rsqrtf(var + 1e-5f);

#if defined(USE_DOT2)
            unsigned qp[4];
#pragma unroll
            for (int j = 0; j < 4; j++) {
                float qa  = (qf[a0 + 2 * j][p]     - mean) * rstd * l1w[a0 + 2 * j]     + l1b[a0 + 2 * j];
                float qbv = (qf[a0 + 2 * j + 1][p] - mean) * rstd * l1w[a0 + 2 * j + 1] + l1b[a0 + 2 * j + 1];
                qp[j] = (unsigned)f2bf(qa) | ((unsigned)f2bf(qbv) << 16);
            }
#define QKDOT(kk) ({ \
    float dd = 0.f; \
    dd = __builtin_amdgcn_fdot2_f32_bf16(__builtin_bit_cast(bf2v, (kk).x), __builtin_bit_cast(bf2v, qp[0]), dd, false); \
    dd = __builtin_amdgcn_fdot2_f32_bf16(__builtin_bit_cast(bf2v, (kk).y), __builtin_bit_cast(bf2v, qp[1]), dd, false); \
    dd = __builtin_amdgcn_fdot2_f32_bf16(__builtin_bit_cast(bf2v, (kk).z), __builtin_bit_cast(bf2v, qp[2]), dd, false); \
    dd = __builtin_amdgcn_fdot2_f32_bf16(__builtin_bit_cast(bf2v, (kk).w), __builtin_bit_cast(bf2v, qp[3]), dd, false); \
    dd; })
#else
            f2 qv[4];
#pragma unroll
            for (int j = 0; j < 4; j++) {
                float qa  = (qf[a0 + 2 * j][p]     - mean) * rstd * l1w[a0 + 2 * j]     + l1b[a0 + 2 * j];
                float qbv = (qf[a0 + 2 * j + 1][p] - mean) * rstd * l1w[a0 + 2 * j + 1] + l1b[a0 + 2 * j + 1];
                qv[j][0] = qa;
                qv[j][1] = qbv;
            }
#define QKDOT(kk) ({ \
    f2 d2 = qv[0] * bfp2f2((kk).x); \
    d2 += qv[1] * bfp2f2((kk).y); \
    d2 += qv[2] * bfp2f2((kk).z); \
    d2 += qv[3] * bfp2f2((kk).w); \
    d2[0] + d2[1]; })
#endif
            // wave-uniform LDS reads: token l chunk at skv + l*256B + h*32B
            const unsigned short* kvl = &skv[h * 16];
            int l0 = half ? 39 : 0;
            int l1 = half ? 77 : 39;
            float ssum = 0.f;
            f2 acc2[4] = {(f2)0.f, (f2)0.f, (f2)0.f, (f2)0.f};
            int l = l0;
            for (; l + 2 <= l1; l += 2) {
                uint4 ka = *(const uint4*)(kvl + (size_t)l * 128);
                uint4 va = *(const uint4*)(kvl + (size_t)l * 128 + 8);
                uint4 kb2 = *(const uint4*)(kvl + (size_t)(l + 1) * 128);
                uint4 vb2 = *(const uint4*)(kvl + (size_t)(l + 1) * 128 + 8);

                float ea = EXP2(QKDOT(ka));
                ssum += ea;
                f2 ea2 = {ea, ea};
                acc2[0] += ea2 * bfp2f2(va.x);
                acc2[1] += ea2 * bfp2f2(va.y);
                acc2[2] += ea2 * bfp2f2(va.z);
                acc2[3] += ea2 * bfp2f2(va.w);

                float eb = EXP2(QKDOT(kb2));
                ssum += eb;
                f2 eb2 = {eb, eb};
                acc2[0] += eb2 * bfp2f2(vb2.x);
                acc2[1] += eb2 * bfp2f2(vb2.y);
                acc2[2] += eb2 * bfp2f2(vb2.z);
                acc2[3] += eb2 * bfp2f2(vb2.w);
            }
            if (l < l1) {
                uint4 kc = *(const uint4*)(kvl + (size_t)l * 128);
                uint4 vc = *(const uint4*)(kvl + (size_t)l * 128 + 8);
                float e = EXP2(QKDOT(kc));
                ssum += e;
                f2 e2 = {e, e};
                acc2[0] += e2 * bfp2f2(vc.x);
                acc2[1] += e2 * bfp2f2(vc.y);
                acc2[2] += e2 * bfp2f2(vc.z);
                acc2[3] += e2 * bfp2f2(vc.w);
            }
#undef QKDOT
            if (half) {
#pragma unroll
                for (int j = 0; j < 4; j++) {
                    so[a0 + 2 * j][p] = acc2[j][0];
                    so[a0 + 2 * j + 1][p] = acc2[j][1];
                }
                ss1[h][p] = ssum;
            }
            __syncthreads();   // B4
            if (!half) {
                float inv = 1.0f / (ssum + ss1[h][p]);
                us8 v;
#pragma unroll
                for (int j = 0; j < 4; j++) {
                    v[2*j]   = f2bf((acc2[j][0] + so[a0 + 2*j][p]) * inv);
                    v[2*j+1] = f2bf((acc2[j][1] + so[a0 + 2*j+1][p]) * inv);
                }
                *(us8*)&sob[p][a0] = v;
            }
        }
        __syncthreads();   // B5

        // ---- D: out-proj GEMM (A from sob), result -> qf (reused as scratch)
        {
            bfrag af0 = *(const bfrag*)&sob[mt * 16 + n16][quad * 8];
            bfrag af1 = *(const bfrag*)&sob[mt * 16 + n16][32 + quad * 8];
            const unsigned short* bo = PO + layer * 4096 + (size_t)((quad * 64) + nt * 16 + n16) * 8;
            bfrag bf0 = *(const bfrag*)bo;
            bfrag bf1 = *(const bfrag*)(bo + 2048);
            ffrag cc = (ffrag)0.f;
            cc = __builtin_amdgcn_mfma_f32_16x16x32_bf16(af0, bf0, cc, 0, 0, 0);
            cc = __builtin_amdgcn_mfma_f32_16x16x32_bf16(af1, bf1, cc, 0, 0, 0);
            int cch = nt * 16 + n16;
            float obv = ob[cch];
            int p0 = mt * 16 + quad * 4;
            float4 o4;
            o4.x = cc[0] + obv; o4.y = cc[1] + obv; o4.z = cc[2] + obv; o4.w = cc[3] + obv;
            *(float4*)&qf[cch][p0] = o4;
        }
        __syncthreads();   // B6

        // ---- E: residual update in regs + refresh bf16 mirror
        {
            us4 v;
#pragma unroll
            for (int j = 0; j < 4; j++) {
                rres[j] += qf[o0 + j][p];
                v[j] = f2bf(rres[j]);
            }
            *(us4*)&sfb[p][o0] = v;
        }
        __syncthreads();   // B7
    }

    // final write: NHWC bf16
    us4 v;
#pragma unroll
    for (int j = 0; j < 4; j++) v[j] = f2bf(rres[j]);
    *(us4*)(X1 + ((size_t)(b * 4096 + n0 + p)) * 64 + o0) = v;
}

// ---------------- upsample conv as 9-tap implicit GEMM, MFMA 16x16x32 bf16.
// MERGED: one 512-thread block covers all 256 n' -> input staged once.
__global__ void __launch_bounds__(512)
upconv_mfma_kernel(const unsigned short* __restrict__ X, const unsigned short* __restrict__ Bp,
                   const float* __restrict__ bias, unsigned short* __restrict__ Y,
                   int Hin, int Win) {
    __shared__ __attribute__((aligned(16))) unsigned short sx[3 * 66 * 72];  // 28.5 KB

    int wv = threadIdx.x >> 6;          // wave 0..7
    int lane = threadIdx.x & 63;
    int q = lane >> 4, n16 = lane & 15;
    int m0 = blockIdx.x * 64;
    int hw = Hin * Win;
    int b = m0 / hw, rem = m0 % hw;
    int h = rem / Win, w0 = rem % Win;
    const unsigned short* Xb = X + (size_t)b * hw * 64;

    // stage 3 rows x 66 px x 64 ch (zero halo), ch-padded to 72
    const us8 z8 = (us8)(unsigned short)0;
    for (int e = threadIdx.x; e < 1584; e += 512) {
        int ch8 = e & 7;
        int pxi = (e >> 3) % 66;
        int row = e / 528;
        int hh = h + row - 1, wp = w0 + pxi - 1;
        us8 v = z8;
        if ((unsigned)hh < (unsigned)Hin && (unsigned)wp < (unsigned)Win)
            v = *(const us8*)(Xb + ((size_t)hh * Win + wp) * 64 + ch8 * 8);
        *(us8*)&sx[row * 4752 + pxi * 72 + ch8 * 8] = v;
    }
    __syncthreads();

    ffrag acc[4][2];
#pragma unroll
    for (int i = 0; i < 4; i++)
#pragma unroll
        for (int j2 = 0; j2 < 2; j2++) acc[i][j2] = (ffrag)0.f;

    int npb = wv * 32;   // n' base for this wave (covers all 256 across 8 waves)

    for (int t = 0; t < 9; t++) {
        int dy = t / 3, dx = t % 3;
        bfrag af[4][2];
#pragma unroll
        for (int mt = 0; mt < 4; mt++) {
            const unsigned short* sp = &sx[dy * 4752 + (mt * 16 + n16 + dx) * 72 + q * 8];
            af[mt][0] = *(const bfrag*)sp;
            af[mt][1] = *(const bfrag*)(sp + 32);
        }
#pragma unroll
        for (int s = 0; s < 2; s++) {
#pragma unroll
            for (int nt = 0; nt < 2; nt++) {
                bfrag bf = *(const bfrag*)(Bp + (size_t)((((t * 2 + s) * 4 + q) * 256) + npb + nt * 16 + n16) * 8);
#pragma unroll
                for (int mt = 0; mt < 4; mt++)
                    acc[mt][nt] = __builtin_amdgcn_mfma_f32_16x16x32_bf16(af[mt][s], bf, acc[mt][nt], 0, 0, 0);
            }
        }
    }

    int g = wv >> 1;                   // g' = 2*r1 + r2
    int r1 = wv >> 2, r2 = (wv >> 1) & 1;
    int cbase = (wv & 1) * 32;
    float bv[2];
#pragma unroll
    for (int nt = 0; nt < 2; nt++) bv[nt] = bias[4 * (cbase + nt * 16 + n16) + g];
    int Wo = Win * 2;
    unsigned short* Yb = Y + ((size_t)b * Hin * 2 * Wo + (size_t)(2 * h + r1) * Wo + r2) * 64;
#pragma unroll
    for (int mt = 0; mt < 4; mt++) {
#pragma unroll
        for (int r = 0; r < 4; r++) {
            int m = mt * 16 + q * 4 + r;   // C/D: row = quad*4 + reg
            unsigned short* dst = Yb + (size_t)(2 * (w0 + m)) * 64;
#pragma unroll
            for (int nt = 0; nt < 2; nt++) {
                float v = acc[mt][nt][r] + bv[nt];
                v = fmaxf(v, 0.f);
                dst[cbase + nt * 16 + n16] = f2bf(v);
            }
        }
    }
}

// ---------------- final conv as 9-tap implicit GEMM, N=16 (3 real), fp32 NCHW out
// 2D tile: 64 px x 4 rows per block; 6 rows x 66 px staged in LDS (57 KB).
__global__ void __launch_bounds__(256)
final_mfma_kernel(const unsigned short* __restrict__ X, const unsigned short* __restrict__ Bp,
                  const float* __restrict__ bias, float* __restrict__ out) {
    __shared__ __attribute__((aligned(16))) unsigned short sx[6 * 66 * 72];  // 57 KB

    int t0 = blockIdx.x;
    int wseg = t0 & 3;
    int rg = (t0 >> 2) & 63;
    int b = t0 >> 8;
    int y0 = rg * 4, w0 = wseg * 64;
    int wv = threadIdx.x >> 6, lane = threadIdx.x & 63;
    int q = lane >> 4, n16 = lane & 15;
    const unsigned short* Xb = X + (size_t)b * 65536 * 64;

    // stage 6 rows x 66 px x 64 ch (zero halo), ch pitch 72
    const us8 z8 = (us8)(unsigned short)0;
    for (int e = threadIdx.x; e < 3168; e += 256) {
        int ch8 = e & 7;
        int pxi = (e >> 3) % 66;
        int row = e / 528;
        int hh = y0 - 1 + row, wp = w0 - 1 + pxi;
        us8 v = z8;
        if ((unsigned)hh < 256u && (unsigned)wp < 256u)
            v = *(const us8*)(Xb + ((size_t)hh * 256 + wp) * 64 + ch8 * 8);
        *(us8*)&sx[row * 4752 + pxi * 72 + ch8 * 8] = v;
    }
    __syncthreads();

    // wave wv handles row y0+wv, 64 px
    ffrag acc[4];
#pragma unroll
    for (int i = 0; i < 4; i++) acc[i] = (ffrag)0.f;

    for (int t = 0; t < 9; t++) {
        int dy = t / 3, dx = t % 3;
        bfrag af[4][2];
#pragma unroll
        for (int mt = 0; mt < 4; mt++) {
            const unsigned short* sp = &sx[(wv + dy) * 4752 + (mt * 16 + n16 + dx) * 72 + q * 8];
            af[mt][0] = *(const bfrag*)sp;
            af[mt][1] = *(const bfrag*)(sp + 32);
        }
#pragma unroll
        for (int s = 0; s < 2; s++) {
            bfrag bf = *(const bfrag*)(Bp + (size_t)((((t * 2 + s) * 4 + q) * 16) + n16) * 8);
#pragma unroll
            for (int mt = 0; mt < 4; mt++)
                acc[mt] = __builtin_amdgcn_mfma_f32_16x16x32_bf16(af[mt][s], bf, acc[mt], 0, 0, 0);
        }
    }

    if (n16 < 3) {
        float bj = bias[n16];
        float* ob = out + (((size_t)b * 3 + n16) * 256 + (y0 + wv)) * 256;
#pragma unroll
        for (int mt = 0; mt < 4; mt++)
#pragma unroll
            for (int r = 0; r < 4; r++)
                ob[w0 + mt * 16 + q * 4 + r] = acc[mt][r] + bj;
    }
}

extern "C" void kernel_launch(void* const* d_in, const int* in_sizes, int n_in,
                              void* d_out, int out_size, void* d_ws, size_t ws_size,
                              hipStream_t stream) {
    const float* x      = (const float*)d_in[0];
    const float* th     = (const float*)d_in[1];
    const float* proj_w = (const float*)d_in[2];
    const float* proj_b = (const float*)d_in[3];
    const float* cf_w   = (const float*)d_in[4];
    const float* cf_b   = (const float*)d_in[5];
    const float* qw     = (const float*)d_in[6];
    const float* qb     = (const float*)d_in[7];
    const float* kw     = (const float*)d_in[8];
    const float* kb     = (const float*)d_in[9];
    const float* vw     = (const float*)d_in[10];
    const float* vb     = (const float*)d_in[11];
    const float* ow     = (const float*)d_in[12];
    const float* ob     = (const float*)d_in[13];
    const float* l1w    = (const float*)d_in[14];
    const float* l1b    = (const float*)d_in[15];
    const float* l2w    = (const float*)d_in[16];
    const float* l2b    = (const float*)d_in[17];
    const float* up_w   = (const float*)d_in[18];
    const float* up_b   = (const float*)d_in[19];
    const float* cl_w   = (const float*)d_in[20];
    const float* cl_b   = (const float*)d_in[21];

    float* ws   = (float*)d_ws;
    float* feat = ws;                         // 2,097,152 f
    float* tf   = feat + 2097152;             // 39,424 f
    unsigned short* kvi = (unsigned short*)(tf + 39424);   // 1,261,568 us (bf16 KV)
    unsigned short* X1  = kvi + 1261568;      // 2,097,152 us
    unsigned short* X2  = X1 + 2097152;       // 8,388,608 us
    unsigned short* X3  = X2 + 8388608;       // 33,554,432 us
    unsigned short* PW1 = X3 + 33554432;      // 147,456 us
    unsigned short* PW2 = PW1 + 147456;       // 147,456 us
    unsigned short* PWF = PW2 + 147456;       // 9,216 us
    unsigned short* PQ  = PWF + 9216;         // 65,536 us
    unsigned short* PO  = PQ + 65536;         // 65,536 us

    hipLaunchKernelGGL(prep_kernel, dim3(8192 + 1152 + 36 + 256), dim3(256), 0, stream,
                       x, cf_w, cf_b, feat, up_w, PW1, PW2, cl_w, PWF, qw, ow, PQ, PO);
    hipLaunchKernelGGL(text_proj_kernel, dim3(BATCH * LTXT), dim3(64), 0, stream,
                       th, proj_w, proj_b, tf);
    hipLaunchKernelGGL(kv_all_kernel, dim3(16 * BATCH * LTXT), dim3(64), 0, stream,
                       tf, kw, kb, vw, vb, l2w, l2b, kvi);

    hipLaunchKernelGGL(attn_all_kernel, dim3(BATCH * (HW0 / 64)), dim3(1024), 0, stream,
                       feat, kvi, PQ, PO, qb, ob, l1w, l1b, X1);

    hipLaunchKernelGGL(upconv_mfma_kernel, dim3(BATCH * 64 * 64 / 64), dim3(512), 0, stream,
                       X1, PW1, up_b, X2, 64, 64);
    hipLaunchKernelGGL(upconv_mfma_kernel, dim3(BATCH * 128 * 128 / 64), dim3(512), 0, stream,
                       X2, PW2, up_b + 256, X3, 128, 128);
    hipLaunchKernelGGL(final_mfma_kernel, dim3(BATCH * 64 * 4), dim3(256), 0, stream,
                       X3, PWF, cl_b, (float*)d_out);
}

// Round 8
// 488.725 us; speedup vs baseline: 1.8716x; 1.1092x over previous
//
#include <hip/hip_runtime.h>
#include <math.h>

#define BATCH 8
#define C 64
#define NH 8
#define HD 8
#define LTXT 77
#define H0 64
#define W0 64
#define HW0 (H0*W0)

typedef __attribute__((ext_vector_type(8))) short bfrag;    // 8 bf16 (4 VGPR)
typedef __attribute__((ext_vector_type(4))) float ffrag;    // 4 fp32 acc
typedef __attribute__((ext_vector_type(8))) unsigned short us8;
typedef __attribute__((ext_vector_type(4))) unsigned short us4;
typedef __attribute__((ext_vector_type(2))) float f2;

#if defined(__has_builtin)
#if __has_builtin(__builtin_amdgcn_exp2f)
#define EXP2(x) __builtin_amdgcn_exp2f(x)
#else
#define EXP2(x) exp2f(x)
#endif
#if __has_builtin(__builtin_amdgcn_fdot2_f32_bf16)
#define USE_DOT2 1
typedef __bf16 bf2v __attribute__((ext_vector_type(2)));
#endif
#else
#define EXP2(x) exp2f(x)
#endif

__device__ __forceinline__ unsigned short f2bf(float f) {
    unsigned u = __builtin_bit_cast(unsigned, f);
    u += 0x7fff + ((u >> 16) & 1);   // RNE
    return (unsigned short)(u >> 16);
}

// unpack a u32 holding 2 bf16 into f2 {lo, hi}
__device__ __forceinline__ f2 bfp2f2(unsigned w) {
    f2 r;
    r[0] = __builtin_bit_cast(float, w << 16);
    r[1] = __builtin_bit_cast(float, w & 0xffff0000u);
    return r;
}

// ---------------- text projection: tf[b,l,c] = th[b,l,:] . proj_w[c,:] + proj_b[c]
__global__ void text_proj_kernel(const float* __restrict__ th, const float* __restrict__ pw,
                                 const float* __restrict__ pb, float* __restrict__ tf) {
    __shared__ float sh[512];
    int bl = blockIdx.x;
    int c = threadIdx.x;
    const float* row = th + (size_t)bl * 512;
    for (int i = c; i < 512; i += 64) sh[i] = row[i];
    __syncthreads();
    const float* wrow = pw + c * 512;
    float acc = pb[c];
    for (int i = 0; i < 512; i += 4) {
        acc += sh[i] * wrow[i] + sh[i+1] * wrow[i+1] + sh[i+2] * wrow[i+2] + sh[i+3] * wrow[i+3];
    }
    tf[bl * 64 + c] = acc;
}

// ---------------- merged prep: conv_in (blocks 0..8191) + pack_up (8192..9343)
// + pack_final (9344..9379) + pack_proj (9380..9635)
__global__ void __launch_bounds__(256)
prep_kernel(const float* __restrict__ x, const float* __restrict__ cf_w,
            const float* __restrict__ cf_b, float* __restrict__ feat,
            const float* __restrict__ up_w,
            unsigned short* __restrict__ PW1, unsigned short* __restrict__ PW2,
            const float* __restrict__ cl_w, unsigned short* __restrict__ PWF,
            const float* __restrict__ qw, const float* __restrict__ ow,
            unsigned short* __restrict__ PQ, unsigned short* __restrict__ PO) {
    int blk = blockIdx.x;
    if (blk < 8192) {
        // conv_in: x[8,3,64,64] -> feat[8,64,64,64] fp32 NCHW
        int idx = blk * 256 + threadIdx.x;
        int wx = idx & 63;
        int h = (idx >> 6) & 63;
        int o = (idx >> 12) & 63;
        int b = idx >> 18;
        const float* wr = cf_w + o * 27;
        float acc = cf_b[o];
        for (int ci = 0; ci < 3; ci++) {
            for (int ky = 0; ky < 3; ky++) {
                int y = h + ky - 1;
                if ((unsigned)y >= 64u) continue;
                const float* xr = x + (((size_t)b * 3 + ci) * 64 + y) * 64;
                const float* wk = wr + ci * 9 + ky * 3;
                if (wx > 0) acc += xr[wx - 1] * wk[0];
                acc += xr[wx] * wk[1];
                if (wx < 63) acc += xr[wx + 1] * wk[2];
            }
        }
        feat[idx] = acc;
    } else if (blk < 8192 + 1152) {
        int e0 = blk - 8192;
        int st = e0 / 576;
        int e = (e0 % 576) * 256 + threadIdx.x;   // < 147456
        const float* w = up_w + (size_t)st * 147456;
        unsigned short* d = st ? PW2 : PW1;
        int j = e & 7, n = (e >> 3) & 255, q = (e >> 11) & 3, s = (e >> 13) & 1, t = e >> 14;
        int c = n & 63, g = n >> 6;
        int co = 4 * c + g, ci = 32 * s + 8 * q + j;
        d[e] = f2bf(w[co * 576 + ci * 9 + t]);
    } else if (blk < 8192 + 1152 + 36) {
        int e = (blk - 8192 - 1152) * 256 + threadIdx.x;   // < 9216
        int j = e & 7, n = (e >> 3) & 15, q = (e >> 7) & 3, s = (e >> 9) & 1, t = e >> 10;
        int ci = 32 * s + 8 * q + j;
        float v = (n < 3) ? cl_w[n * 576 + ci * 9 + t] : 0.f;
        PWF[e] = f2bf(v);
    } else {
        int e = (blk - 8192 - 1152 - 36) * 256 + threadIdx.x;   // < 65536
        int j = e & 7, n = (e >> 3) & 63, quad = (e >> 9) & 3, kt = (e >> 11) & 1, layer = e >> 12;
        int c = kt * 32 + quad * 8 + j;
        PQ[e] = f2bf(qw[layer * 4096 + n * 64 + c]);
        PO[e] = f2bf(ow[layer * 4096 + n * 64 + c]);
    }
}

// ---------------- K/V for ALL 16 blocks upfront; K pre-scaled by scale*log2(e).
// Split layouts: kb16[layer][b][tok][head][8] bf16 (16B chunk per (tok,head));
// vbuf[layer][b][tok][head][8] fp32 (32B chunk). 3-token s_load groups in attn
// then need only 12 live SGPRs/token (vs 16 fp32-interleaved) -> 3-deep fits.
__global__ void kv_all_kernel(const float* __restrict__ tf,
                              const float* __restrict__ kw, const float* __restrict__ kb,
                              const float* __restrict__ vw, const float* __restrict__ vb,
                              const float* __restrict__ l2w, const float* __restrict__ l2b,
                              unsigned short* __restrict__ kb16, float* __restrict__ vbuf) {
    __shared__ float sh[64];
    int g = blockIdx.x;
    int bl = g % (BATCH * LTXT);
    int blk = g / (BATCH * LTXT);
    int o = threadIdx.x;
    sh[o] = tf[bl * 64 + o];
    __syncthreads();
    const float* kr = kw + blk * 4096 + o * 64;
    const float* vr = vw + blk * 4096 + o * 64;
    float ka = kb[blk * 64 + o], va = vb[blk * 64 + o];
    for (int c2 = 0; c2 < 64; c2++) {
        float t = sh[c2];
        ka += t * kr[c2];
        va += t * vr[c2];
    }
    float s = ka;
    for (int off = 32; off; off >>= 1) s += __shfl_xor(s, off, 64);
    float mean = s * (1.0f / 64.0f);
    float d = ka - mean;
    float s2 = d * d;
    for (int off = 32; off; off >>= 1) s2 += __shfl_xor(s2, off, 64);
    float rstd = rsqrtf(s2 * (1.0f / 64.0f) + 1e-5f);
    float kn = (d * rstd * l2w[blk * 64 + o] + l2b[blk * 64 + o]) * 0.51006973f;
    size_t ti = (size_t)blk * (BATCH * LTXT) + bl;   // global token row
    kb16[ti * 64 + o] = f2bf(kn);                    // o = head*8 + ch already
    vbuf[ti * 64 + o] = va;
}

// ---------------- ALL 16 attention blocks fused, 1024 threads = 16 waves.
// R5 structure (measured-best). Token loop: 3 tokens/iter; per token K is a
// 16B bf16 s_load (4 SGPR) consumed via fdot2, V a 32B fp32 s_load (8 SGPR)
// -> 36 live KV SGPRs for the 3-group (R5's 48 was refused, 32 accepted).
// Waits drop 0.5 -> 0.33/token with zero added per-token VALU.
__global__ void __launch_bounds__(1024, 8)
attn_all_kernel(const float* __restrict__ feat,
                const unsigned short* __restrict__ kb16, const float* __restrict__ vbuf,
                const unsigned short* __restrict__ PQ, const unsigned short* __restrict__ PO,
                const float* __restrict__ qb_a, const float* __restrict__ ob_a,
                const float* __restrict__ l1w_a, const float* __restrict__ l1b_a,
                unsigned short* __restrict__ X1) {
    __shared__ __attribute__((aligned(16))) unsigned short sfb[64][72]; // residual bf16 [p][c]
    __shared__ __attribute__((aligned(16))) unsigned short sob[64][72]; // attn-out bf16 [p][c]
    __shared__ __attribute__((aligned(16))) float qf[64][68];           // raw q / out-proj [c][p]
    __shared__ float so[64][64];        // half-1 raw acc exchange [c][p]
    __shared__ __attribute__((aligned(16))) float red[2][4][64];        // LN partials [s][nt][p]
    __shared__ float ss1[8][64];        // half-1 softmax denominators

    int b = blockIdx.x >> 6;
    int tile = blockIdx.x & 63;
    int n0 = tile << 6;
    int wv = __builtin_amdgcn_readfirstlane(threadIdx.x >> 6);  // wave 0..15
    int lane = threadIdx.x & 63;
    int p = lane;
    int quad = lane >> 4, n16 = lane & 15;
    int mt = wv >> 2, nt = wv & 3;      // GEMM C-tile role
    int o0 = wv * 4;                    // ownership role: channels o0..o0+3, pixel p
    int h = wv >> 1, half = wv & 1;     // attention role
    int a0 = h * 8;
    const float* fbase = feat + ((size_t)b << 18) + n0;

    // stage: residual regs + bf16 mirror
    float rres[4];
#pragma unroll
    for (int j = 0; j < 4; j++) rres[j] = fbase[(o0 + j) * HW0 + p];
    {
        us4 v;
#pragma unroll
        for (int j = 0; j < 4; j++) v[j] = f2bf(rres[j]);
        *(us4*)&sfb[p][o0] = v;
    }

    const float pxk = 0.05f / 63.0f;
    float py005 = (float)tile * pxk;
    __syncthreads();

#pragma unroll 1
    for (int layer = 0; layer < 16; layer++) {
        const float* qb = qb_a + layer * 64;
        const float* ob = ob_a + layer * 64;
        const float* l1w = l1w_a + layer * 64;
        const float* l1b = l1b_a + layer * 64;

        // ---- A: q-proj GEMM + in-wave LN partial reduction in epilogue
        {
            bfrag af0 = *(const bfrag*)&sfb[mt * 16 + n16][quad * 8];
            bfrag af1 = *(const bfrag*)&sfb[mt * 16 + n16][32 + quad * 8];
            const unsigned short* bq = PQ + layer * 4096 + (size_t)((quad * 64) + nt * 16 + n16) * 8;
            bfrag bf0 = *(const bfrag*)bq;
            bfrag bf1 = *(const bfrag*)(bq + 2048);   // kt=1 chunk
            ffrag cc = (ffrag)0.f;
            cc = __builtin_amdgcn_mfma_f32_16x16x32_bf16(af0, bf0, cc, 0, 0, 0);
            cc = __builtin_amdgcn_mfma_f32_16x16x32_bf16(af1, bf1, cc, 0, 0, 0);
            int cch = nt * 16 + n16;
            float qbv = qb[cch];
            int p0 = mt * 16 + quad * 4;
            float pe0 = (nt < 2) ? (float)p0 * pxk : py005;
            float ped = (nt < 2) ? pxk : 0.f;
            float ov[4];
            ov[0] = cc[0] + qbv + pe0;
            ov[1] = cc[1] + qbv + pe0 + ped;
            ov[2] = cc[2] + qbv + pe0 + 2.f * ped;
            ov[3] = cc[3] + qbv + pe0 + 3.f * ped;
            float4 o4 = {ov[0], ov[1], ov[2], ov[3]};
            *(float4*)&qf[cch][p0] = o4;

            // channel-sum over the 16 n16 lanes (same quad), per pixel r
            float sv[4], sq[4];
#pragma unroll
            for (int r = 0; r < 4; r++) {
                float s = ov[r], s2v = ov[r] * ov[r];
                s += __shfl_xor(s, 1);  s2v += __shfl_xor(s2v, 1);
                s += __shfl_xor(s, 2);  s2v += __shfl_xor(s2v, 2);
                s += __shfl_xor(s, 4);  s2v += __shfl_xor(s2v, 4);
                s += __shfl_xor(s, 8);  s2v += __shfl_xor(s2v, 8);
                sv[r] = s; sq[r] = s2v;
            }
            if (n16 == 0) {
                *(float4*)&red[0][nt][p0] = (float4){sv[0], sv[1], sv[2], sv[3]};
                *(float4*)&red[1][nt][p0] = (float4){sq[0], sq[1], sq[2], sq[3]};
            }
        }
        __syncthreads();   // B1

        // ---- C: attention, wave = (head, token-half); stats + normalize inline
        {
            float ts = red[0][0][p] + red[0][1][p] + red[0][2][p] + red[0][3][p];
            float ts2 = red[1][0][p] + red[1][1][p] + red[1][2][p] + red[1][3][p];
            float mean = ts * (1.0f / 64.0f);
            float var = ts2 * (1.0f / 64.0f) - mean * mean;
            float rstd = rsqrtf(var + 1e-5f);

#if defined(USE_DOT2)
            unsigned qp[4];
#pragma unroll
            for (int j = 0; j < 4; j++) {
                float qa  = (qf[a0 + 2 * j][p]     - mean) * rstd * l1w[a0 + 2 * j]     + l1b[a0 + 2 * j];
                float qbv = (qf[a0 + 2 * j + 1][p] - mean) * rstd * l1w[a0 + 2 * j + 1] + l1b[a0 + 2 * j + 1];
                qp[j] = (unsigned)f2bf(qa) | ((unsigned)f2bf(qbv) << 16);
            }
#define QKDOT(kk) ({ \
    float dd = 0.f; \
    dd = __builtin_amdgcn_fdot2_f32_bf16(__builtin_bit_cast(bf2v, (kk).x), __builtin_bit_cast(bf2v, qp[0]), dd, false); \
    dd = __builtin_amdgcn_fdot2_f32_bf16(__builtin_bit_cast(bf2v, (kk).y), __builtin_bit_cast(bf2v, qp[1]), dd, false); \
    dd = __builtin_amdgcn_fdot2_f32_bf16(__builtin_bit_cast(bf2v, (kk).z), __builtin_bit_cast(bf2v, qp[2]), dd, false); \
    dd = __builtin_amdgcn_fdot2_f32_bf16(__builtin_bit_cast(bf2v, (kk).w), __builtin_bit_cast(bf2v, qp[3]), dd, false); \
    dd; })
#else
            f2 qv[4];
#pragma unroll
            for (int j = 0; j < 4; j++) {
                float qa  = (qf[a0 + 2 * j][p]     - mean) * rstd * l1w[a0 + 2 * j]     + l1b[a0 + 2 * j];
                float qbv = (qf[a0 + 2 * j + 1][p] - mean) * rstd * l1w[a0 + 2 * j + 1] + l1b[a0 + 2 * j + 1];
                qv[j][0] = qa;
                qv[j][1] = qbv;
            }
#define QKDOT(kk) ({ \
    f2 d2 = qv[0] * bfp2f2((kk).x); \
    d2 += qv[1] * bfp2f2((kk).y); \
    d2 += qv[2] * bfp2f2((kk).z); \
    d2 += qv[3] * bfp2f2((kk).w); \
    d2[0] + d2[1]; })
#endif
            size_t tbase = (size_t)layer * BATCH * LTXT + (size_t)b * LTXT;
            const unsigned short* kb_b = kb16 + tbase * 64 + a0;   // 16B bf16 chunks
            const float* vb_b = vbuf + tbase * 64 + a0;            // 32B fp32 chunks
            int l0 = half ? 39 : 0;
            int l1 = half ? 77 : 39;
            float ssum = 0.f;
            f2 acc2[4] = {(f2)0.f, (f2)0.f, (f2)0.f, (f2)0.f};
            int l = l0;
            for (; l + 3 <= l1; l += 3) {
                // 3 tokens: 3x(K dwordx4 + V dwordx8) issued up front, 1 wait
                uint4  kA = *(const uint4*)(kb_b + (size_t)l * 64);
                uint4  kB = *(const uint4*)(kb_b + (size_t)(l + 1) * 64);
                uint4  kC = *(const uint4*)(kb_b + (size_t)(l + 2) * 64);
                float4 vA0 = *(const float4*)(vb_b + (size_t)l * 64);
                float4 vA1 = *(const float4*)(vb_b + (size_t)l * 64 + 4);
                float4 vB0 = *(const float4*)(vb_b + (size_t)(l + 1) * 64);
                float4 vB1 = *(const float4*)(vb_b + (size_t)(l + 1) * 64 + 4);
                float4 vC0 = *(const float4*)(vb_b + (size_t)(l + 2) * 64);
                float4 vC1 = *(const float4*)(vb_b + (size_t)(l + 2) * 64 + 4);

                float ea = EXP2(QKDOT(kA));
                ssum += ea;
                f2 ea2 = {ea, ea};
                acc2[0] += ea2 * (f2){vA0.x, vA0.y};
                acc2[1] += ea2 * (f2){vA0.z, vA0.w};
                acc2[2] += ea2 * (f2){vA1.x, vA1.y};
                acc2[3] += ea2 * (f2){vA1.z, vA1.w};

                float eb = EXP2(QKDOT(kB));
                ssum += eb;
                f2 eb2 = {eb, eb};
                acc2[0] += eb2 * (f2){vB0.x, vB0.y};
                acc2[1] += eb2 * (f2){vB0.z, vB0.w};
                acc2[2] += eb2 * (f2){vB1.x, vB1.y};
                acc2[3] += eb2 * (f2){vB1.z, vB1.w};

                float ec = EXP2(QKDOT(kC));
                ssum += ec;
                f2 ec2 = {ec, ec};
                acc2[0] += ec2 * (f2){vC0.x, vC0.y};
                acc2[1] += ec2 * (f2){vC0.z, vC0.w};
                acc2[2] += ec2 * (f2){vC1.x, vC1.y};
                acc2[3] += ec2 * (f2){vC1.z, vC1.w};
            }
            for (; l < l1; l++) {
                uint4  kD = *(const uint4*)(kb_b + (size_t)l * 64);
                float4 vD0 = *(const float4*)(vb_b + (size_t)l * 64);
                float4 vD1 = *(const float4*)(vb_b + (size_t)l * 64 + 4);
                float e = EXP2(QKDOT(kD));
                ssum += e;
                f2 e2 = {e, e};
                acc2[0] += e2 * (f2){vD0.x, vD0.y};
                acc2[1] += e2 * (f2){vD0.z, vD0.w};
                acc2[2] += e2 * (f2){vD1.x, vD1.y};
                acc2[3] += e2 * (f2){vD1.z, vD1.w};
            }
#undef QKDOT
            if (half) {
#pragma unroll
                for (int j = 0; j < 4; j++) {
                    so[a0 + 2 * j][p] = acc2[j][0];
                    so[a0 + 2 * j + 1][p] = acc2[j][1];
                }
                ss1[h][p] = ssum;
            }
            __syncthreads();   // B4
            if (!half) {
                float inv = 1.0f / (ssum + ss1[h][p]);
                us8 v;
#pragma unroll
                for (int j = 0; j < 4; j++) {
                    v[2*j]   = f2bf((acc2[j][0] + so[a0 + 2*j][p]) * inv);
                    v[2*j+1] = f2bf((acc2[j][1] + so[a0 + 2*j+1][p]) * inv);
                }
                *(us8*)&sob[p][a0] = v;
            }
        }
        __syncthreads();   // B5

        // ---- D: out-proj GEMM (A from sob), result -> qf (reused as scratch)
        {
            bfrag af0 = *(const bfrag*)&sob[mt * 16 + n16][quad * 8];
            bfrag af1 = *(const bfrag*)&sob[mt * 16 + n16][32 + quad * 8];
            const unsigned short* bo = PO + layer * 4096 + (size_t)((quad * 64) + nt * 16 + n16) * 8;
            bfrag bf0 = *(const bfrag*)bo;
            bfrag bf1 = *(const bfrag*)(bo + 2048);
            ffrag cc = (ffrag)0.f;
            cc = __builtin_amdgcn_mfma_f32_16x16x32_bf16(af0, bf0, cc, 0, 0, 0);
            cc = __builtin_amdgcn_mfma_f32_16x16x32_bf16(af1, bf1, cc, 0, 0, 0);
            int cch = nt * 16 + n16;
            float obv = ob[cch];
            int p0 = mt * 16 + quad * 4;
            float4 o4;
            o4.x = cc[0] + obv; o4.y = cc[1] + obv; o4.z = cc[2] + obv; o4.w = cc[3] + obv;
            *(float4*)&qf[cch][p0] = o4;
        }
        __syncthreads();   // B6

        // ---- E: residual update in regs + refresh bf16 mirror
        {
            us4 v;
#pragma unroll
            for (int j = 0; j < 4; j++) {
                rres[j] += qf[o0 + j][p];
                v[j] = f2bf(rres[j]);
            }
            *(us4*)&sfb[p][o0] = v;
        }
        __syncthreads();   // B7
    }

    // final write: NHWC bf16
    us4 v;
#pragma unroll
    for (int j = 0; j < 4; j++) v[j] = f2bf(rres[j]);
    *(us4*)(X1 + ((size_t)(b * 4096 + n0 + p)) * 64 + o0) = v;
}

// ---------------- upsample conv as 9-tap implicit GEMM, MFMA 16x16x32 bf16.
// MERGED: one 512-thread block covers all 256 n' -> input staged once.
__global__ void __launch_bounds__(512)
upconv_mfma_kernel(const unsigned short* __restrict__ X, const unsigned short* __restrict__ Bp,
                   const float* __restrict__ bias, unsigned short* __restrict__ Y,
                   int Hin, int Win) {
    __shared__ __attribute__((aligned(16))) unsigned short sx[3 * 66 * 72];  // 28.5 KB

    int wv = threadIdx.x >> 6;          // wave 0..7
    int lane = threadIdx.x & 63;
    int q = lane >> 4, n16 = lane & 15;
    int m0 = blockIdx.x * 64;
    int hw = Hin * Win;
    int b = m0 / hw, rem = m0 % hw;
    int h = rem / Win, w0 = rem % Win;
    const unsigned short* Xb = X + (size_t)b * hw * 64;

    // stage 3 rows x 66 px x 64 ch (zero halo), ch-padded to 72
    const us8 z8 = (us8)(unsigned short)0;
    for (int e = threadIdx.x; e < 1584; e += 512) {
        int ch8 = e & 7;
        int pxi = (e >> 3) % 66;
        int row = e / 528;
        int hh = h + row - 1, wp = w0 + pxi - 1;
        us8 v = z8;
        if ((unsigned)hh < (unsigned)Hin && (unsigned)wp < (unsigned)Win)
            v = *(const us8*)(Xb + ((size_t)hh * Win + wp) * 64 + ch8 * 8);
        *(us8*)&sx[row * 4752 + pxi * 72 + ch8 * 8] = v;
    }
    __syncthreads();

    ffrag acc[4][2];
#pragma unroll
    for (int i = 0; i < 4; i++)
#pragma unroll
        for (int j2 = 0; j2 < 2; j2++) acc[i][j2] = (ffrag)0.f;

    int npb = wv * 32;   // n' base for this wave (covers all 256 across 8 waves)

    for (int t = 0; t < 9; t++) {
        int dy = t / 3, dx = t % 3;
        bfrag af[4][2];
#pragma unroll
        for (int mt = 0; mt < 4; mt++) {
            const unsigned short* sp = &sx[dy * 4752 + (mt * 16 + n16 + dx) * 72 + q * 8];
            af[mt][0] = *(const bfrag*)sp;
            af[mt][1] = *(const bfrag*)(sp + 32);
        }
#pragma unroll
        for (int s = 0; s < 2; s++) {
#pragma unroll
            for (int nt = 0; nt < 2; nt++) {
                bfrag bf = *(const bfrag*)(Bp + (size_t)((((t * 2 + s) * 4 + q) * 256) + npb + nt * 16 + n16) * 8);
#pragma unroll
                for (int mt = 0; mt < 4; mt++)
                    acc[mt][nt] = __builtin_amdgcn_mfma_f32_16x16x32_bf16(af[mt][s], bf, acc[mt][nt], 0, 0, 0);
            }
        }
    }

    int g = wv >> 1;                   // g' = 2*r1 + r2
    int r1 = wv >> 2, r2 = (wv >> 1) & 1;
    int cbase = (wv & 1) * 32;
    float bv[2];
#pragma unroll
    for (int nt = 0; nt < 2; nt++) bv[nt] = bias[4 * (cbase + nt * 16 + n16) + g];
    int Wo = Win * 2;
    unsigned short* Yb = Y + ((size_t)b * Hin * 2 * Wo + (size_t)(2 * h + r1) * Wo + r2) * 64;
#pragma unroll
    for (int mt = 0; mt < 4; mt++) {
#pragma unroll
        for (int r = 0; r < 4; r++) {
            int m = mt * 16 + q * 4 + r;   // C/D: row = quad*4 + reg
            unsigned short* dst = Yb + (size_t)(2 * (w0 + m)) * 64;
#pragma unroll
            for (int nt = 0; nt < 2; nt++) {
                float v = acc[mt][nt][r] + bv[nt];
                v = fmaxf(v, 0.f);
                dst[cbase + nt * 16 + n16] = f2bf(v);
            }
        }
    }
}

// ---------------- final conv as 9-tap implicit GEMM, N=16 (3 real), fp32 NCHW out
// 2D tile: 64 px x 4 rows per block; 6 rows x 66 px staged in LDS (57 KB).
__global__ void __launch_bounds__(256)
final_mfma_kernel(const unsigned short* __restrict__ X, const unsigned short* __restrict__ Bp,
                  const float* __restrict__ bias, float* __restrict__ out) {
    __shared__ __attribute__((aligned(16))) unsigned short sx[6 * 66 * 72];  // 57 KB

    int t0 = blockIdx.x;
    int wseg = t0 & 3;
    int rg = (t0 >> 2) & 63;
    int b = t0 >> 8;
    int y0 = rg * 4, w0 = wseg * 64;
    int wv = threadIdx.x >> 6, lane = threadIdx.x & 63;
    int q = lane >> 4, n16 = lane & 15;
    const unsigned short* Xb = X + (size_t)b * 65536 * 64;

    // stage 6 rows x 66 px x 64 ch (zero halo), ch pitch 72
    const us8 z8 = (us8)(unsigned short)0;
    for (int e = threadIdx.x; e < 3168; e += 256) {
        int ch8 = e & 7;
        int pxi = (e >> 3) % 66;
        int row = e / 528;
        int hh = y0 - 1 + row, wp = w0 - 1 + pxi;
        us8 v = z8;
        if ((unsigned)hh < 256u && (unsigned)wp < 256u)
            v = *(const us8*)(Xb + ((size_t)hh * 256 + wp) * 64 + ch8 * 8);
        *(us8*)&sx[row * 4752 + pxi * 72 + ch8 * 8] = v;
    }
    __syncthreads();

    // wave wv handles row y0+wv, 64 px
    ffrag acc[4];
#pragma unroll
    for (int i = 0; i < 4; i++) acc[i] = (ffrag)0.f;

    for (int t = 0; t < 9; t++) {
        int dy = t / 3, dx = t % 3;
        bfrag af[4][2];
#pragma unroll
        for (int mt = 0; mt < 4; mt++) {
            const unsigned short* sp = &sx[(wv + dy) * 4752 + (mt * 16 + n16 + dx) * 72 + q * 8];
            af[mt][0] = *(const bfrag*)sp;
            af[mt][1] = *(const bfrag*)(sp + 32);
        }
#pragma unroll
        for (int s = 0; s < 2; s++) {
            bfrag bf = *(const bfrag*)(Bp + (size_t)((((t * 2 + s) * 4 + q) * 16) + n16) * 8);
#pragma unroll
            for (int mt = 0; mt < 4; mt++)
                acc[mt] = __builtin_amdgcn_mfma_f32_16x16x32_bf16(af[mt][s], bf, acc[mt], 0, 0, 0);
        }
    }

    if (n16 < 3) {
        float bj = bias[n16];
        float* ob = out + (((size_t)b * 3 + n16) * 256 + (y0 + wv)) * 256;
#pragma unroll
        for (int mt = 0; mt < 4; mt++)
#pragma unroll
            for (int r = 0; r < 4; r++)
                ob[w0 + mt * 16 + q * 4 + r] = acc[mt][r] + bj;
    }
}

extern "C" void kernel_launch(void* const* d_in, const int* in_sizes, int n_in,
                              void* d_out, int out_size, void* d_ws, size_t ws_size,
                              hipStream_t stream) {
    const float* x      = (const float*)d_in[0];
    const float* th     = (const float*)d_in[1];
    const float* proj_w = (const float*)d_in[2];
    const float* proj_b = (const float*)d_in[3];
    const float* cf_w   = (const float*)d_in[4];
    const float* cf_b   = (const float*)d_in[5];
    const float* qw     = (const float*)d_in[6];
    const float* qb     = (const float*)d_in[7];
    const float* kw     = (const float*)d_in[8];
    const float* kb     = (const float*)d_in[9];
    const float* vw     = (const float*)d_in[10];
    const float* vb     = (const float*)d_in[11];
    const float* ow     = (const float*)d_in[12];
    const float* ob     = (const float*)d_in[13];
    const float* l1w    = (const float*)d_in[14];
    const float* l1b    = (const float*)d_in[15];
    const float* l2w    = (const float*)d_in[16];
    const float* l2b    = (const float*)d_in[17];
    const float* up_w   = (const float*)d_in[18];
    const float* up_b   = (const float*)d_in[19];
    const float* cl_w   = (const float*)d_in[20];
    const float* cl_b   = (const float*)d_in[21];

    float* ws   = (float*)d_ws;
    float* feat = ws;                         // 2,097,152 f
    float* tf   = feat + 2097152;             // 39,424 f
    float* vbuf = tf + 39424;                 // 630,784 f
    unsigned short* kb16 = (unsigned short*)(vbuf + 630784);  // 630,784 us
    unsigned short* X1  = kb16 + 630784;      // 2,097,152 us
    unsigned short* X2  = X1 + 2097152;       // 8,388,608 us
    unsigned short* X3  = X2 + 8388608;       // 33,554,432 us
    unsigned short* PW1 = X3 + 33554432;      // 147,456 us
    unsigned short* PW2 = PW1 + 147456;       // 147,456 us
    unsigned short* PWF = PW2 + 147456;       // 9,216 us
    unsigned short* PQ  = PWF + 9216;         // 65,536 us
    unsigned short* PO  = PQ + 65536;         // 65,536 us

    hipLaunchKernelGGL(prep_kernel, dim3(8192 + 1152 + 36 + 256), dim3(256), 0, stream,
                       x, cf_w, cf_b, feat, up_w, PW1, PW2, cl_w, PWF, qw, ow, PQ, PO);
    hipLaunchKernelGGL(text_proj_kernel, dim3(BATCH * LTXT), dim3(64), 0, stream,
                       th, proj_w, proj_b, tf);
    hipLaunchKernelGGL(kv_all_kernel, dim3(16 * BATCH * LTXT), dim3(64), 0, stream,
                       tf, kw, kb, vw, vb, l2w, l2b, kb16, vbuf);

    hipLaunchKernelGGL(attn_all_kernel, dim3(BATCH * (HW0 / 64)), dim3(1024), 0, stream,
                       feat, kb16, vbuf, PQ, PO, qb, ob, l1w, l1b, X1);

    hipLaunchKernelGGL(upconv_mfma_kernel, dim3(BATCH * 64 * 64 / 64), dim3(512), 0, stream,
                       X1, PW1, up_b, X2, 64, 64);
    hipLaunchKernelGGL(upconv_mfma_kernel, dim3(BATCH * 128 * 128 / 64), dim3(512), 0, stream,
                       X2, PW2, up_b + 256, X3, 128, 128);
    hipLaunchKernelGGL(final_mfma_kernel, dim3(BATCH * 64 * 4), dim3(256), 0, stream,
                       X3, PWF, cl_b, (float*)d_out);
}

// Round 9
// 487.356 us; speedup vs baseline: 1.8768x; 1.0028x over previous
//
#include <hip/hip_runtime.h>
#include <math.h>

#define BATCH 8
#define C 64
#define NH 8
#define HD 8
#define LTXT 77
#define H0 64
#define W0 64
#define HW0 (H0*W0)

typedef __attribute__((ext_vector_type(8))) short bfrag;    // 8 bf16 (4 VGPR)
typedef __attribute__((ext_vector_type(4))) float ffrag;    // 4 fp32 acc
typedef __attribute__((ext_vector_type(8))) unsigned short us8;
typedef __attribute__((ext_vector_type(4))) unsigned short us4;
typedef __attribute__((ext_vector_type(2))) float f2;

#if defined(__has_builtin)
#if __has_builtin(__builtin_amdgcn_exp2f)
#define EXP2(x) __builtin_amdgcn_exp2f(x)
#else
#define EXP2(x) exp2f(x)
#endif
#else
#define EXP2(x) exp2f(x)
#endif

__device__ __forceinline__ unsigned short f2bf(float f) {
    unsigned u = __builtin_bit_cast(unsigned, f);
    u += 0x7fff + ((u >> 16) & 1);   // RNE
    return (unsigned short)(u >> 16);
}

// ---------------- text projection: tf[b,l,c] = th[b,l,:] . proj_w[c,:] + proj_b[c]
__global__ void text_proj_kernel(const float* __restrict__ th, const float* __restrict__ pw,
                                 const float* __restrict__ pb, float* __restrict__ tf) {
    __shared__ float sh[512];
    int bl = blockIdx.x;
    int c = threadIdx.x;
    const float* row = th + (size_t)bl * 512;
    for (int i = c; i < 512; i += 64) sh[i] = row[i];
    __syncthreads();
    const float* wrow = pw + c * 512;
    float acc = pb[c];
    for (int i = 0; i < 512; i += 4) {
        acc += sh[i] * wrow[i] + sh[i+1] * wrow[i+1] + sh[i+2] * wrow[i+2] + sh[i+3] * wrow[i+3];
    }
    tf[bl * 64 + c] = acc;
}

// ---------------- merged prep: conv_in (blocks 0..8191) + pack_up (8192..9343)
// + pack_final (9344..9379) + pack_proj (9380..9635)
__global__ void __launch_bounds__(256)
prep_kernel(const float* __restrict__ x, const float* __restrict__ cf_w,
            const float* __restrict__ cf_b, float* __restrict__ feat,
            const float* __restrict__ up_w,
            unsigned short* __restrict__ PW1, unsigned short* __restrict__ PW2,
            const float* __restrict__ cl_w, unsigned short* __restrict__ PWF,
            const float* __restrict__ qw, const float* __restrict__ ow,
            unsigned short* __restrict__ PQ, unsigned short* __restrict__ PO) {
    int blk = blockIdx.x;
    if (blk < 8192) {
        // conv_in: x[8,3,64,64] -> feat[8,64,64,64] fp32 NCHW
        int idx = blk * 256 + threadIdx.x;
        int wx = idx & 63;
        int h = (idx >> 6) & 63;
        int o = (idx >> 12) & 63;
        int b = idx >> 18;
        const float* wr = cf_w + o * 27;
        float acc = cf_b[o];
        for (int ci = 0; ci < 3; ci++) {
            for (int ky = 0; ky < 3; ky++) {
                int y = h + ky - 1;
                if ((unsigned)y >= 64u) continue;
                const float* xr = x + (((size_t)b * 3 + ci) * 64 + y) * 64;
                const float* wk = wr + ci * 9 + ky * 3;
                if (wx > 0) acc += xr[wx - 1] * wk[0];
                acc += xr[wx] * wk[1];
                if (wx < 63) acc += xr[wx + 1] * wk[2];
            }
        }
        feat[idx] = acc;
    } else if (blk < 8192 + 1152) {
        int e0 = blk - 8192;
        int st = e0 / 576;
        int e = (e0 % 576) * 256 + threadIdx.x;   // < 147456
        const float* w = up_w + (size_t)st * 147456;
        unsigned short* d = st ? PW2 : PW1;
        int j = e & 7, n = (e >> 3) & 255, q = (e >> 11) & 3, s = (e >> 13) & 1, t = e >> 14;
        int c = n & 63, g = n >> 6;
        int co = 4 * c + g, ci = 32 * s + 8 * q + j;
        d[e] = f2bf(w[co * 576 + ci * 9 + t]);
    } else if (blk < 8192 + 1152 + 36) {
        int e = (blk - 8192 - 1152) * 256 + threadIdx.x;   // < 9216
        int j = e & 7, n = (e >> 3) & 15, q = (e >> 7) & 3, s = (e >> 9) & 1, t = e >> 10;
        int ci = 32 * s + 8 * q + j;
        float v = (n < 3) ? cl_w[n * 576 + ci * 9 + t] : 0.f;
        PWF[e] = f2bf(v);
    } else {
        int e = (blk - 8192 - 1152 - 36) * 256 + threadIdx.x;   // < 65536
        int j = e & 7, n = (e >> 3) & 63, quad = (e >> 9) & 3, kt = (e >> 11) & 1, layer = e >> 12;
        int c = kt * 32 + quad * 8 + j;
        PQ[e] = f2bf(qw[layer * 4096 + n * 64 + c]);
        PO[e] = f2bf(ow[layer * 4096 + n * 64 + c]);
    }
}

// ---------------- K/V for ALL 16 blocks upfront; K pre-scaled by scale*log2(e).
// Interleaved kv[layer][b][tok][head][16] = {k0..k7, v0..v7} so the attention
// loop fetches one aligned 64B wave-uniform chunk per token (1 s_load).
__global__ void kv_all_kernel(const float* __restrict__ tf,
                              const float* __restrict__ kw, const float* __restrict__ kb,
                              const float* __restrict__ vw, const float* __restrict__ vb,
                              const float* __restrict__ l2w, const float* __restrict__ l2b,
                              float* __restrict__ kvbuf) {
    __shared__ float sh[64];
    int g = blockIdx.x;
    int bl = g % (BATCH * LTXT);
    int blk = g / (BATCH * LTXT);
    int o = threadIdx.x;
    sh[o] = tf[bl * 64 + o];
    __syncthreads();
    const float* kr = kw + blk * 4096 + o * 64;
    const float* vr = vw + blk * 4096 + o * 64;
    float ka = kb[blk * 64 + o], va = vb[blk * 64 + o];
    for (int c2 = 0; c2 < 64; c2++) {
        float t = sh[c2];
        ka += t * kr[c2];
        va += t * vr[c2];
    }
    float s = ka;
    for (int off = 32; off; off >>= 1) s += __shfl_xor(s, off, 64);
    float mean = s * (1.0f / 64.0f);
    float d = ka - mean;
    float s2 = d * d;
    for (int off = 32; off; off >>= 1) s2 += __shfl_xor(s2, off, 64);
    float rstd = rsqrtf(s2 * (1.0f / 64.0f) + 1e-5f);
    float kn = (d * rstd * l2w[blk * 64 + o] + l2b[blk * 64 + o]) * 0.51006973f;
    // interleaved write: token row = 128 floats = 8 heads x {8 k, 8 v}
    size_t base = ((size_t)blk * (BATCH * LTXT) + bl) * 128;
    int hd = o >> 3, ch = o & 7;
    kvbuf[base + hd * 16 + ch]     = kn;
    kvbuf[base + hd * 16 + 8 + ch] = va;
}

// ---------------- ALL 16 attention blocks fused, 1024 threads = 16 waves.
// R5-verbatim (best measured: 233 us). SMEM s_load prefetch depth is
// compiler-capped at ~2 tokens (R5/R8 SGPR=80 tell); 4 structural attempts
// to deepen it all regressed -> locked.
__global__ void __launch_bounds__(1024, 8)
attn_all_kernel(const float* __restrict__ feat,
                const float* __restrict__ kvbuf,
                const unsigned short* __restrict__ PQ, const unsigned short* __restrict__ PO,
                const float* __restrict__ qb_a, const float* __restrict__ ob_a,
                const float* __restrict__ l1w_a, const float* __restrict__ l1b_a,
                unsigned short* __restrict__ X1) {
    __shared__ __attribute__((aligned(16))) unsigned short sfb[64][72]; // residual bf16 [p][c]
    __shared__ __attribute__((aligned(16))) unsigned short sob[64][72]; // attn-out bf16 [p][c]
    __shared__ __attribute__((aligned(16))) float qf[64][68];           // raw q / out-proj [c][p]
    __shared__ float so[64][64];        // half-1 raw acc exchange [c][p]
    __shared__ __attribute__((aligned(16))) float red[2][4][64];        // LN partials [s][nt][p]
    __shared__ float ss1[8][64];        // half-1 softmax denominators

    int b = blockIdx.x >> 6;
    int tile = blockIdx.x & 63;
    int n0 = tile << 6;
    int wv = __builtin_amdgcn_readfirstlane(threadIdx.x >> 6);  // wave 0..15
    int lane = threadIdx.x & 63;
    int p = lane;
    int quad = lane >> 4, n16 = lane & 15;
    int mt = wv >> 2, nt = wv & 3;      // GEMM C-tile role
    int o0 = wv * 4;                    // ownership role: channels o0..o0+3, pixel p
    int h = wv >> 1, half = wv & 1;     // attention role
    int a0 = h * 8;
    const float* fbase = feat + ((size_t)b << 18) + n0;

    // stage: residual regs + bf16 mirror
    float rres[4];
#pragma unroll
    for (int j = 0; j < 4; j++) rres[j] = fbase[(o0 + j) * HW0 + p];
    {
        us4 v;
#pragma unroll
        for (int j = 0; j < 4; j++) v[j] = f2bf(rres[j]);
        *(us4*)&sfb[p][o0] = v;
    }

    const float pxk = 0.05f / 63.0f;
    float py005 = (float)tile * pxk;
    __syncthreads();

#pragma unroll 1
    for (int layer = 0; layer < 16; layer++) {
        const float* qb = qb_a + layer * 64;
        const float* ob = ob_a + layer * 64;
        const float* l1w = l1w_a + layer * 64;
        const float* l1b = l1b_a + layer * 64;

        // ---- A: q-proj GEMM + in-wave LN partial reduction in epilogue
        {
            bfrag af0 = *(const bfrag*)&sfb[mt * 16 + n16][quad * 8];
            bfrag af1 = *(const bfrag*)&sfb[mt * 16 + n16][32 + quad * 8];
            const unsigned short* bq = PQ + layer * 4096 + (size_t)((quad * 64) + nt * 16 + n16) * 8;
            bfrag bf0 = *(const bfrag*)bq;
            bfrag bf1 = *(const bfrag*)(bq + 2048);   // kt=1 chunk
            ffrag cc = (ffrag)0.f;
            cc = __builtin_amdgcn_mfma_f32_16x16x32_bf16(af0, bf0, cc, 0, 0, 0);
            cc = __builtin_amdgcn_mfma_f32_16x16x32_bf16(af1, bf1, cc, 0, 0, 0);
            int cch = nt * 16 + n16;
            float qbv = qb[cch];
            int p0 = mt * 16 + quad * 4;
            float pe0 = (nt < 2) ? (float)p0 * pxk : py005;
            float ped = (nt < 2) ? pxk : 0.f;
            float ov[4];
            ov[0] = cc[0] + qbv + pe0;
            ov[1] = cc[1] + qbv + pe0 + ped;
            ov[2] = cc[2] + qbv + pe0 + 2.f * ped;
            ov[3] = cc[3] + qbv + pe0 + 3.f * ped;
            float4 o4 = {ov[0], ov[1], ov[2], ov[3]};
            *(float4*)&qf[cch][p0] = o4;

            // channel-sum over the 16 n16 lanes (same quad), per pixel r
            float sv[4], sq[4];
#pragma unroll
            for (int r = 0; r < 4; r++) {
                float s = ov[r], s2v = ov[r] * ov[r];
                s += __shfl_xor(s, 1);  s2v += __shfl_xor(s2v, 1);
                s += __shfl_xor(s, 2);  s2v += __shfl_xor(s2v, 2);
                s += __shfl_xor(s, 4);  s2v += __shfl_xor(s2v, 4);
                s += __shfl_xor(s, 8);  s2v += __shfl_xor(s2v, 8);
                sv[r] = s; sq[r] = s2v;
            }
            if (n16 == 0) {
                *(float4*)&red[0][nt][p0] = (float4){sv[0], sv[1], sv[2], sv[3]};
                *(float4*)&red[1][nt][p0] = (float4){sq[0], sq[1], sq[2], sq[3]};
            }
        }
        __syncthreads();   // B1

        // ---- C: attention, wave = (head, token-half); stats + normalize inline
        {
            float ts = red[0][0][p] + red[0][1][p] + red[0][2][p] + red[0][3][p];
            float ts2 = red[1][0][p] + red[1][1][p] + red[1][2][p] + red[1][3][p];
            float mean = ts * (1.0f / 64.0f);
            float var = ts2 * (1.0f / 64.0f) - mean * mean;
            float rstd = rsqrtf(var + 1e-5f);

            f2 qv[4];
#pragma unroll
            for (int j = 0; j < 4; j++) {
                float qa  = (qf[a0 + 2 * j][p]     - mean) * rstd * l1w[a0 + 2 * j]     + l1b[a0 + 2 * j];
                float qbv = (qf[a0 + 2 * j + 1][p] - mean) * rstd * l1w[a0 + 2 * j + 1] + l1b[a0 + 2 * j + 1];
                qv[j][0] = qa;
                qv[j][1] = qbv;
            }
            // interleaved K+V: one 64B wave-uniform chunk per token
            const float* kvb = kvbuf + ((size_t)layer * BATCH * LTXT + (size_t)b * LTXT) * 128 + h * 16;
            int l0 = half ? 39 : 0;
            int l1 = half ? 77 : 39;
            float ssum = 0.f;
            f2 acc2[4] = {(f2)0.f, (f2)0.f, (f2)0.f, (f2)0.f};
            int l = l0;
            for (; l + 3 <= l1; l += 3) {
                // three 64B chunks loaded up front
                const float4* ra = (const float4*)(kvb + (size_t)l * 128);
                const float4* rb = (const float4*)(kvb + (size_t)(l + 1) * 128);
                const float4* rc = (const float4*)(kvb + (size_t)(l + 2) * 128);
                float4 ka0 = ra[0], ka1 = ra[1], va0 = ra[2], va1 = ra[3];
                float4 kb0 = rb[0], kb1 = rb[1], vb0 = rb[2], vb1 = rb[3];
                float4 kc0 = rc[0], kc1 = rc[1], vc0 = rc[2], vc1 = rc[3];

                f2 da = qv[0] * (f2){ka0.x, ka0.y};
                da += qv[1] * (f2){ka0.z, ka0.w};
                da += qv[2] * (f2){ka1.x, ka1.y};
                da += qv[3] * (f2){ka1.z, ka1.w};
                float ea = EXP2(da[0] + da[1]);
                ssum += ea;
                f2 ea2 = {ea, ea};
                acc2[0] += ea2 * (f2){va0.x, va0.y};
                acc2[1] += ea2 * (f2){va0.z, va0.w};
                acc2[2] += ea2 * (f2){va1.x, va1.y};
                acc2[3] += ea2 * (f2){va1.z, va1.w};

                f2 db = qv[0] * (f2){kb0.x, kb0.y};
                db += qv[1] * (f2){kb0.z, kb0.w};
                db += qv[2] * (f2){kb1.x, kb1.y};
                db += qv[3] * (f2){kb1.z, kb1.w};
                float eb = EXP2(db[0] + db[1]);
                ssum += eb;
                f2 eb2 = {eb, eb};
                acc2[0] += eb2 * (f2){vb0.x, vb0.y};
                acc2[1] += eb2 * (f2){vb0.z, vb0.w};
                acc2[2] += eb2 * (f2){vb1.x, vb1.y};
                acc2[3] += eb2 * (f2){vb1.z, vb1.w};

                f2 dc = qv[0] * (f2){kc0.x, kc0.y};
                dc += qv[1] * (f2){kc0.z, kc0.w};
                dc += qv[2] * (f2){kc1.x, kc1.y};
                dc += qv[3] * (f2){kc1.z, kc1.w};
                float ec = EXP2(dc[0] + dc[1]);
                ssum += ec;
                f2 ec2 = {ec, ec};
                acc2[0] += ec2 * (f2){vc0.x, vc0.y};
                acc2[1] += ec2 * (f2){vc0.z, vc0.w};
                acc2[2] += ec2 * (f2){vc1.x, vc1.y};
                acc2[3] += ec2 * (f2){vc1.z, vc1.w};
            }
            for (; l < l1; l++) {
                const float4* r = (const float4*)(kvb + (size_t)l * 128);
                float4 k0 = r[0], k1 = r[1], v0 = r[2], v1 = r[3];
                f2 d2 = qv[0] * (f2){k0.x, k0.y};
                d2 += qv[1] * (f2){k0.z, k0.w};
                d2 += qv[2] * (f2){k1.x, k1.y};
                d2 += qv[3] * (f2){k1.z, k1.w};
                float e = EXP2(d2[0] + d2[1]);
                ssum += e;
                f2 e2 = {e, e};
                acc2[0] += e2 * (f2){v0.x, v0.y};
                acc2[1] += e2 * (f2){v0.z, v0.w};
                acc2[2] += e2 * (f2){v1.x, v1.y};
                acc2[3] += e2 * (f2){v1.z, v1.w};
            }
            if (half) {
#pragma unroll
                for (int j = 0; j < 4; j++) {
                    so[a0 + 2 * j][p] = acc2[j][0];
                    so[a0 + 2 * j + 1][p] = acc2[j][1];
                }
                ss1[h][p] = ssum;
            }
            __syncthreads();   // B4
            if (!half) {
                float inv = 1.0f / (ssum + ss1[h][p]);
                us8 v;
#pragma unroll
                for (int j = 0; j < 4; j++) {
                    v[2*j]   = f2bf((acc2[j][0] + so[a0 + 2*j][p]) * inv);
                    v[2*j+1] = f2bf((acc2[j][1] + so[a0 + 2*j+1][p]) * inv);
                }
                *(us8*)&sob[p][a0] = v;
            }
        }
        __syncthreads();   // B5

        // ---- D: out-proj GEMM (A from sob), result -> qf (reused as scratch)
        {
            bfrag af0 = *(const bfrag*)&sob[mt * 16 + n16][quad * 8];
            bfrag af1 = *(const bfrag*)&sob[mt * 16 + n16][32 + quad * 8];
            const unsigned short* bo = PO + layer * 4096 + (size_t)((quad * 64) + nt * 16 + n16) * 8;
            bfrag bf0 = *(const bfrag*)bo;
            bfrag bf1 = *(const bfrag*)(bo + 2048);
            ffrag cc = (ffrag)0.f;
            cc = __builtin_amdgcn_mfma_f32_16x16x32_bf16(af0, bf0, cc, 0, 0, 0);
            cc = __builtin_amdgcn_mfma_f32_16x16x32_bf16(af1, bf1, cc, 0, 0, 0);
            int cch = nt * 16 + n16;
            float obv = ob[cch];
            int p0 = mt * 16 + quad * 4;
            float4 o4;
            o4.x = cc[0] + obv; o4.y = cc[1] + obv; o4.z = cc[2] + obv; o4.w = cc[3] + obv;
            *(float4*)&qf[cch][p0] = o4;
        }
        __syncthreads();   // B6

        // ---- E: residual update in regs + refresh bf16 mirror
        {
            us4 v;
#pragma unroll
            for (int j = 0; j < 4; j++) {
                rres[j] += qf[o0 + j][p];
                v[j] = f2bf(rres[j]);
            }
            *(us4*)&sfb[p][o0] = v;
        }
        __syncthreads();   // B7
    }

    // final write: NHWC bf16
    us4 v;
#pragma unroll
    for (int j = 0; j < 4; j++) v[j] = f2bf(rres[j]);
    *(us4*)(X1 + ((size_t)(b * 4096 + n0 + p)) * 64 + o0) = v;
}

// ---------------- upsample conv as 9-tap implicit GEMM, MFMA 16x16x32 bf16.
// NEW: 2 output rows per block (stage 4 rows x 66 px = 38 KB) -> staging
// halo 3.09x -> 2.06x per output px, half the blocks. Wave = (row ri, shuffle
// group g): all 64 channels of group g for row ri; acc[4][4].
// Per-output MFMA sequence identical to before -> bit-identical output.
__global__ void __launch_bounds__(512)
upconv_mfma_kernel(const unsigned short* __restrict__ X, const unsigned short* __restrict__ Bp,
                   const float* __restrict__ bias, unsigned short* __restrict__ Y,
                   int Hin, int Win) {
    __shared__ __attribute__((aligned(16))) unsigned short sx[4 * 66 * 72];  // 38 KB

    int wv = threadIdx.x >> 6;          // wave 0..7
    int lane = threadIdx.x & 63;
    int q = lane >> 4, n16 = lane & 15;
    int tiles_w = Win >> 6;
    int t0 = blockIdx.x;
    int wseg = t0 % tiles_w;
    int h2 = (t0 / tiles_w) % (Hin >> 1);
    int b = t0 / (tiles_w * (Hin >> 1));
    int h0 = h2 * 2, w0 = wseg * 64;
    const unsigned short* Xb = X + (size_t)b * Hin * Win * 64;

    // stage 4 rows x 66 px x 64 ch (zero halo), ch-padded to 72
    const us8 z8 = (us8)(unsigned short)0;
    for (int e = threadIdx.x; e < 2112; e += 512) {
        int ch8 = e & 7;
        int pxi = (e >> 3) % 66;
        int row = e / 528;
        int hh = h0 + row - 1, wp = w0 + pxi - 1;
        us8 v = z8;
        if ((unsigned)hh < (unsigned)Hin && (unsigned)wp < (unsigned)Win)
            v = *(const us8*)(Xb + ((size_t)hh * Win + wp) * 64 + ch8 * 8);
        *(us8*)&sx[row * 4752 + pxi * 72 + ch8 * 8] = v;
    }
    __syncthreads();

    ffrag acc[4][4];
#pragma unroll
    for (int i = 0; i < 4; i++)
#pragma unroll
        for (int j2 = 0; j2 < 4; j2++) acc[i][j2] = (ffrag)0.f;

    int ri = wv >> 2;                  // output row within block (0/1)
    int g = wv & 3;                    // shuffle group
    int npb = g * 64;                  // n' base: channels 0..63 of group g

    for (int t = 0; t < 9; t++) {
        int dy = t / 3, dx = t % 3;
        bfrag af[4][2];
#pragma unroll
        for (int mt = 0; mt < 4; mt++) {
            const unsigned short* sp = &sx[(ri + dy) * 4752 + (mt * 16 + n16 + dx) * 72 + q * 8];
            af[mt][0] = *(const bfrag*)sp;
            af[mt][1] = *(const bfrag*)(sp + 32);
        }
#pragma unroll
        for (int s = 0; s < 2; s++) {
#pragma unroll
            for (int nt = 0; nt < 4; nt++) {
                bfrag bf = *(const bfrag*)(Bp + (size_t)((((t * 2 + s) * 4 + q) * 256) + npb + nt * 16 + n16) * 8);
#pragma unroll
                for (int mt = 0; mt < 4; mt++)
                    acc[mt][nt] = __builtin_amdgcn_mfma_f32_16x16x32_bf16(af[mt][s], bf, acc[mt][nt], 0, 0, 0);
            }
        }
    }

    int r1 = g >> 1, r2 = g & 1;
    float bv[4];
#pragma unroll
    for (int nt = 0; nt < 4; nt++) bv[nt] = bias[4 * (nt * 16 + n16) + g];
    int Wo = Win * 2;
    unsigned short* Yb = Y + ((size_t)b * Hin * 2 * Wo + (size_t)(2 * (h0 + ri) + r1) * Wo + r2) * 64;
#pragma unroll
    for (int mt = 0; mt < 4; mt++) {
#pragma unroll
        for (int r = 0; r < 4; r++) {
            int m = mt * 16 + q * 4 + r;   // C/D: row = quad*4 + reg
            unsigned short* dst = Yb + (size_t)(2 * (w0 + m)) * 64;
#pragma unroll
            for (int nt = 0; nt < 4; nt++) {
                float v = acc[mt][nt][r] + bv[nt];
                v = fmaxf(v, 0.f);
                dst[nt * 16 + n16] = f2bf(v);
            }
        }
    }
}

// ---------------- final conv as 9-tap implicit GEMM, N=16 (3 real), fp32 NCHW out
// 2D tile: 64 px x 4 rows per block; 6 rows x 66 px staged in LDS (57 KB).
__global__ void __launch_bounds__(256)
final_mfma_kernel(const unsigned short* __restrict__ X, const unsigned short* __restrict__ Bp,
                  const float* __restrict__ bias, float* __restrict__ out) {
    __shared__ __attribute__((aligned(16))) unsigned short sx[6 * 66 * 72];  // 57 KB

    int t0 = blockIdx.x;
    int wseg = t0 & 3;
    int rg = (t0 >> 2) & 63;
    int b = t0 >> 8;
    int y0 = rg * 4, w0 = wseg * 64;
    int wv = threadIdx.x >> 6, lane = threadIdx.x & 63;
    int q = lane >> 4, n16 = lane & 15;
    const unsigned short* Xb = X + (size_t)b * 65536 * 64;

    // stage 6 rows x 66 px x 64 ch (zero halo), ch pitch 72
    const us8 z8 = (us8)(unsigned short)0;
    for (int e = threadIdx.x; e < 3168; e += 256) {
        int ch8 = e & 7;
        int pxi = (e >> 3) % 66;
        int row = e / 528;
        int hh = y0 - 1 + row, wp = w0 - 1 + pxi;
        us8 v = z8;
        if ((unsigned)hh < 256u && (unsigned)wp < 256u)
            v = *(const us8*)(Xb + ((size_t)hh * 256 + wp) * 64 + ch8 * 8);
        *(us8*)&sx[row * 4752 + pxi * 72 + ch8 * 8] = v;
    }
    __syncthreads();

    // wave wv handles row y0+wv, 64 px
    ffrag acc[4];
#pragma unroll
    for (int i = 0; i < 4; i++) acc[i] = (ffrag)0.f;

    for (int t = 0; t < 9; t++) {
        int dy = t / 3, dx = t % 3;
        bfrag af[4][2];
#pragma unroll
        for (int mt = 0; mt < 4; mt++) {
            const unsigned short* sp = &sx[(wv + dy) * 4752 + (mt * 16 + n16 + dx) * 72 + q * 8];
            af[mt][0] = *(const bfrag*)sp;
            af[mt][1] = *(const bfrag*)(sp + 32);
        }
#pragma unroll
        for (int s = 0; s < 2; s++) {
            bfrag bf = *(const bfrag*)(Bp + (size_t)((((t * 2 + s) * 4 + q) * 16) + n16) * 8);
#pragma unroll
            for (int mt = 0; mt < 4; mt++)
                acc[mt] = __builtin_amdgcn_mfma_f32_16x16x32_bf16(af[mt][s], bf, acc[mt], 0, 0, 0);
        }
    }

    if (n16 < 3) {
        float bj = bias[n16];
        float* ob = out + (((size_t)b * 3 + n16) * 256 + (y0 + wv)) * 256;
#pragma unroll
        for (int mt = 0; mt < 4; mt++)
#pragma unroll
            for (int r = 0; r < 4; r++)
                ob[w0 + mt * 16 + q * 4 + r] = acc[mt][r] + bj;
    }
}

extern "C" void kernel_launch(void* const* d_in, const int* in_sizes, int n_in,
                              void* d_out, int out_size, void* d_ws, size_t ws_size,
                              hipStream_t stream) {
    const float* x      = (const float*)d_in[0];
    const float* th     = (const float*)d_in[1];
    const float* proj_w = (const float*)d_in[2];
    const float* proj_b = (const float*)d_in[3];
    const float* cf_w   = (const float*)d_in[4];
    const float* cf_b   = (const float*)d_in[5];
    const float* qw     = (const float*)d_in[6];
    const float* qb     = (const float*)d_in[7];
    const float* kw     = (const float*)d_in[8];
    const float* kb     = (const float*)d_in[9];
    const float* vw     = (const float*)d_in[10];
    const float* vb     = (const float*)d_in[11];
    const float* ow     = (const float*)d_in[12];
    const float* ob     = (const float*)d_in[13];
    const float* l1w    = (const float*)d_in[14];
    const float* l1b    = (const float*)d_in[15];
    const float* l2w    = (const float*)d_in[16];
    const float* l2b    = (const float*)d_in[17];
    const float* up_w   = (const float*)d_in[18];
    const float* up_b   = (const float*)d_in[19];
    const float* cl_w   = (const float*)d_in[20];
    const float* cl_b   = (const float*)d_in[21];

    float* ws   = (float*)d_ws;
    float* feat = ws;                         // 2,097,152 f
    float* tf   = feat + 2097152;             // 39,424 f
    float* kvbuf = tf + 39424;                // 1,261,568 f (16*8*77*128)
    unsigned short* X1  = (unsigned short*)(kvbuf + 1261568);  // 2,097,152 us
    unsigned short* X2  = X1 + 2097152;       // 8,388,608 us
    unsigned short* X3  = X2 + 8388608;       // 33,554,432 us
    unsigned short* PW1 = X3 + 33554432;      // 147,456 us
    unsigned short* PW2 = PW1 + 147456;       // 147,456 us
    unsigned short* PWF = PW2 + 147456;       // 9,216 us
    unsigned short* PQ  = PWF + 9216;         // 65,536 us
    unsigned short* PO  = PQ + 65536;         // 65,536 us

    hipLaunchKernelGGL(prep_kernel, dim3(8192 + 1152 + 36 + 256), dim3(256), 0, stream,
                       x, cf_w, cf_b, feat, up_w, PW1, PW2, cl_w, PWF, qw, ow, PQ, PO);
    hipLaunchKernelGGL(text_proj_kernel, dim3(BATCH * LTXT), dim3(64), 0, stream,
                       th, proj_w, proj_b, tf);
    hipLaunchKernelGGL(kv_all_kernel, dim3(16 * BATCH * LTXT), dim3(64), 0, stream,
                       tf, kw, kb, vw, vb, l2w, l2b, kvbuf);

    hipLaunchKernelGGL(attn_all_kernel, dim3(BATCH * (HW0 / 64)), dim3(1024), 0, stream,
                       feat, kvbuf, PQ, PO, qb, ob, l1w, l1b, X1);

    // 2 rows/block: grid = B * (Hin/2) * (Win/64)
    hipLaunchKernelGGL(upconv_mfma_kernel, dim3(BATCH * 32 * 1), dim3(512), 0, stream,
                       X1, PW1, up_b, X2, 64, 64);
    hipLaunchKernelGGL(upconv_mfma_kernel, dim3(BATCH * 64 * 2), dim3(512), 0, stream,
                       X2, PW2, up_b + 256, X3, 128, 128);
    hipLaunchKernelGGL(final_mfma_kernel, dim3(BATCH * 64 * 4), dim3(256), 0, stream,
                       X3, PWF, cl_b, (float*)d_out);
}